// Round 2
// baseline (1100.694 us; speedup 1.0000x reference)
//
#include <hip/hip_runtime.h>

#define NN 100000
#define EE 250000
#define CAP 32

typedef unsigned int u32;

// H = X @ W  (X: [NN,128] f32, W: [128,128] f32), plus attention scalars
// aS[n][h] = sum_c H[n][h*32+c]*atts[h][c], same for aD.
// X staged TRANSPOSED in LDS so the 4 row-values per k are one ds_read_b128
// (was 4 scalar ds_read_b32 -> LDS-issue-bound).
__global__ __launch_bounds__(256) void gemm_att(
    const float* __restrict__ X, const float* __restrict__ W,
    const float* __restrict__ atts, const float* __restrict__ attd,
    float* __restrict__ H, float* __restrict__ aS, float* __restrict__ aD)
{
    __shared__ float sW[64 * 128];    // 32 KB (half of W at a time)
    __shared__ float sXT[128 * 32];   // 16 KB transposed: [k][row]
    const int tid = threadIdx.x;
    const size_t r0 = (size_t)blockIdx.x * 32;

    {   // stage X tile (32 rows x 128) transposed
        int rl = tid & 31, kg = tid >> 5;   // kg 0..7
        const float4* Xr = (const float4*)(X + (r0 + rl) * 128);
#pragma unroll
        for (int t = 0; t < 4; ++t) {
            float4 u = Xr[kg * 4 + t];
            int k = kg * 16 + t * 4;
            sXT[(k + 0) * 32 + rl] = u.x;
            sXT[(k + 1) * 32 + rl] = u.y;
            sXT[(k + 2) * 32 + rl] = u.z;
            sXT[(k + 3) * 32 + rl] = u.w;
        }
    }

    const int jg = tid & 31;   // 4 cols: jg*4 .. jg*4+3
    const int rg = tid >> 5;   // 4 rows: rg*4 .. rg*4+3
    float acc[4][4] = {};

    for (int kh = 0; kh < 2; ++kh) {
        __syncthreads();
        const float4* Wu = (const float4*)(W + kh * 64 * 128);
        float4* sWv = (float4*)sW;
#pragma unroll
        for (int t = 0; t < 8; ++t)
            sWv[tid + 256 * t] = Wu[tid + 256 * t];
        __syncthreads();
#pragma unroll 4
        for (int k = 0; k < 64; ++k) {
            const float4 w = ((const float4*)sW)[k * 32 + jg];
            const int kk = kh * 64 + k;
            const float4 x = ((const float4*)sXT)[kk * 8 + rg];  // rows rg*4..+3
            acc[0][0] += w.x * x.x; acc[0][1] += w.y * x.x; acc[0][2] += w.z * x.x; acc[0][3] += w.w * x.x;
            acc[1][0] += w.x * x.y; acc[1][1] += w.y * x.y; acc[1][2] += w.z * x.y; acc[1][3] += w.w * x.y;
            acc[2][0] += w.x * x.z; acc[2][1] += w.y * x.z; acc[2][2] += w.z * x.z; acc[2][3] += w.w * x.z;
            acc[3][0] += w.x * x.w; acc[3][1] += w.y * x.w; acc[3][2] += w.z * x.w; acc[3][3] += w.w * x.w;
        }
    }

    const float4 sv = ((const float4*)atts)[jg];   // atts[jg*4 .. +3]
    const float4 dv = ((const float4*)attd)[jg];
    const int h = jg >> 3;                          // head = (jg*4)>>5

#pragma unroll
    for (int i = 0; i < 4; ++i) {
        const size_t row = r0 + rg * 4 + i;
        if (H)
            ((float4*)H)[row * 32 + jg] = make_float4(acc[i][0], acc[i][1], acc[i][2], acc[i][3]);
        float ps = acc[i][0] * sv.x + acc[i][1] * sv.y + acc[i][2] * sv.z + acc[i][3] * sv.w;
        float pd = acc[i][0] * dv.x + acc[i][1] * dv.y + acc[i][2] * dv.z + acc[i][3] * dv.w;
        // reduce across 8 consecutive lanes sharing (row, head)
        ps += __shfl_xor(ps, 1); ps += __shfl_xor(ps, 2); ps += __shfl_xor(ps, 4);
        pd += __shfl_xor(pd, 1); pd += __shfl_xor(pd, 2); pd += __shfl_xor(pd, 4);
        if ((jg & 7) == 0) {
            aS[row * 4 + h] = ps;
            aD[row * 4 + h] = pd;
        }
    }
}

// Wf[k][h] = sum_c W[k][h*32+c] * att[h][c]   (fold attention vector into W)
__global__ __launch_bounds__(256) void fold_w(
    const float* __restrict__ W, const float* __restrict__ att,
    float* __restrict__ Wf)
{
    int i = blockIdx.x * 256 + threadIdx.x;
    if (i >= 512) return;
    int k = i >> 2, h = i & 3;
    float s = 0.f;
#pragma unroll
    for (int c = 0; c < 32; ++c)
        s += W[k * 128 + h * 32 + c] * att[h * 32 + c];
    Wf[k * 4 + h] = s;
}

// aD[n][h] = sum_k X[n][k] * Wf[k][h] — dst-side attention scalar without
// the full GEMM. 32 lanes per row, coalesced float4 reads; memory-bound on X.
__global__ __launch_bounds__(256) void gemv_att(
    const float* __restrict__ X, const float* __restrict__ Wf,
    float* __restrict__ aD)
{
    __shared__ float sWf[512];
    const int tid = threadIdx.x;
    if (tid < 128)
        ((float4*)sWf)[tid] = ((const float4*)Wf)[tid];
    __syncthreads();
    const int t = blockIdx.x * 256 + tid;
    const int n = t >> 5, lane = t & 31;
    if (n >= NN) return;
    const float4 x = ((const float4*)X)[(size_t)n * 32 + lane];
    const float4 w0 = ((const float4*)sWf)[lane * 4 + 0];
    const float4 w1 = ((const float4*)sWf)[lane * 4 + 1];
    const float4 w2 = ((const float4*)sWf)[lane * 4 + 2];
    const float4 w3 = ((const float4*)sWf)[lane * 4 + 3];
    float p0 = x.x * w0.x + x.y * w1.x + x.z * w2.x + x.w * w3.x;
    float p1 = x.x * w0.y + x.y * w1.y + x.z * w2.y + x.w * w3.y;
    float p2 = x.x * w0.z + x.y * w1.z + x.z * w2.z + x.w * w3.z;
    float p3 = x.x * w0.w + x.y * w1.w + x.z * w2.w + x.w * w3.w;
#pragma unroll
    for (int off = 1; off < 32; off <<= 1) {
        p0 += __shfl_xor(p0, off);
        p1 += __shfl_xor(p1, off);
        p2 += __shfl_xor(p2, off);
        p3 += __shfl_xor(p3, off);
    }
    if (lane == 0)
        ((float4*)aD)[n] = make_float4(p0, p1, p2, p3);
}

// per-dst incoming-edge buckets (gather-based aggregation; no feature atomics)
__global__ __launch_bounds__(256) void fill_buckets(
    const int* __restrict__ ei, int* __restrict__ deg, int* __restrict__ bkt)
{
    int e = blockIdx.x * 256 + threadIdx.x;
    if (e >= EE) return;
    int s = ei[e], d = ei[EE + e];
    int slot = atomicAdd(&deg[d], 1);
    if (slot >= 0 && slot < CAP) bkt[(size_t)d * CAP + slot] = s;  // P(deg>32)~1e-19
}

// 32 lanes own one dst node: softmax over its in-edges + weighted gather.
__global__ __launch_bounds__(256) void aggregate(
    const int* __restrict__ deg, const int* __restrict__ bkt,
    const float* __restrict__ aS, const float* __restrict__ aD,
    const float* __restrict__ Hs, float* __restrict__ out,
    int accumulate, const float* __restrict__ b1, const float* __restrict__ b2,
    int act)
{
    int t = blockIdx.x * 256 + threadIdx.x;
    int d = t >> 5, lane = t & 31;
    if (d >= NN) return;
    int g = deg[d]; if (g > CAP) g = CAP; if (g < 0) g = 0;
    const int h = lane >> 3;
    const float adh = aD[d * 4 + h];
    const int* mybkt = bkt + (size_t)d * CAP;

    float m = -INFINITY;
    for (int j = 0; j < g; ++j) {
        int s = mybkt[j];
        float e = aS[s * 4 + h] + adh;
        e = e > 0.f ? e : 0.2f * e;
        m = fmaxf(m, e);
    }
    float4 acc = make_float4(0.f, 0.f, 0.f, 0.f);
    float z = 0.f;
    for (int j = 0; j < g; ++j) {
        int s = mybkt[j];
        float e = aS[s * 4 + h] + adh;
        e = e > 0.f ? e : 0.2f * e;
        float w = __expf(e - m);
        z += w;
        float4 hv = ((const float4*)Hs)[(size_t)s * 32 + lane];
        acc.x += w * hv.x; acc.y += w * hv.y; acc.z += w * hv.z; acc.w += w * hv.w;
    }
    float inv = 1.f / (z + 1e-16f);
    acc.x *= inv; acc.y *= inv; acc.z *= inv; acc.w *= inv;

    if (accumulate) {
        float4 p = ((const float4*)out)[(size_t)d * 32 + lane];
        acc.x += p.x; acc.y += p.y; acc.z += p.z; acc.w += p.w;
    }
    if (b1) {
        float4 bv = ((const float4*)b1)[lane];
        acc.x += bv.x; acc.y += bv.y; acc.z += bv.z; acc.w += bv.w;
    }
    if (b2) {
        float4 bv = ((const float4*)b2)[lane];
        acc.x += bv.x; acc.y += bv.y; acc.z += bv.z; acc.w += bv.w;
    }
    if (act) {
        acc.x = acc.x > 0.f ? acc.x : 0.01f * acc.x;
        acc.y = acc.y > 0.f ? acc.y : 0.01f * acc.y;
        acc.z = acc.z > 0.f ? acc.z : 0.01f * acc.z;
        acc.w = acc.w > 0.f ? acc.w : 0.01f * acc.w;
    }
    ((float4*)out)[(size_t)d * 32 + lane] = acc;
}

// pad lin_W [128,349] f32 -> f32 [128,352]; lin_b -> f32 [352]
__global__ __launch_bounds__(256) void pad_w(
    const float* __restrict__ Wl, const float* __restrict__ bl,
    float* __restrict__ Wp, float* __restrict__ bp)
{
    int i = blockIdx.x * 256 + threadIdx.x;
    if (i >= 128 * 352) return;
    int k = i / 352, j = i - k * 352;
    Wp[i] = (j < 349) ? Wl[k * 349 + j] : 0.0f;
    if (i < 352) bp[i] = (i < 349) ? bl[i] : 0.0f;
}

// out[100000,349] f32 = X[100000,128] f32 @ Wp[128,352] f32 + bp
// 128 rows/block, 8x8 register blocking: per k-step a wave issues 64 FMAs
// against 2 ds_read_b128 + 512B of W from L2 (was 16 FMAs per 16B W -> the
// 4.9 GB of duplicated W reads from L2 were the 201us; now ~0.6 GB).
__global__ __launch_bounds__(256) void gemm_out(
    const float* __restrict__ X, const float* __restrict__ Wp,
    const float* __restrict__ bp, float* __restrict__ out)
{
    __shared__ float sXT[128 * 128];   // transposed: [k][row], 64 KB
    const int tid = threadIdx.x;
    const size_t r0 = (size_t)blockIdx.x * 128;
    {
        int rl = tid & 127, g = tid >> 7;   // g 0..1 (col-half of the row)
        size_t row = r0 + rl;
        const float4* Xr = (const float4*)(X + row * 128);
        const bool valid = row < NN;
#pragma unroll
        for (int t = 0; t < 16; ++t) {
            float4 u = valid ? Xr[g * 16 + t] : make_float4(0.f, 0.f, 0.f, 0.f);
            int k = (g * 16 + t) * 4;
            sXT[(k + 0) * 128 + rl] = u.x;
            sXT[(k + 1) * 128 + rl] = u.y;
            sXT[(k + 2) * 128 + rl] = u.z;
            sXT[(k + 3) * 128 + rl] = u.w;
        }
    }
    __syncthreads();
    const int jg = tid & 15;    // 8 cols: j .. j+7
    const int rg = tid >> 4;    // 8 rows: rg*8 .. rg*8+7
    for (int jt = 0; jt < 352; jt += 128) {
        const int j = jt + jg * 8;
        if (j >= 352) continue;          // partial last tile (96 cols)
        float a[8][8] = {};
#pragma unroll 2
        for (int k = 0; k < 128; ++k) {
            const float4 x0 = ((const float4*)sXT)[k * 32 + rg * 2];
            const float4 x1 = ((const float4*)sXT)[k * 32 + rg * 2 + 1];
            const float4 w0 = *(const float4*)(Wp + k * 352 + j);
            const float4 w1 = *(const float4*)(Wp + k * 352 + j + 4);
            const float xr[8] = {x0.x, x0.y, x0.z, x0.w, x1.x, x1.y, x1.z, x1.w};
            const float wc[8] = {w0.x, w0.y, w0.z, w0.w, w1.x, w1.y, w1.z, w1.w};
#pragma unroll
            for (int i = 0; i < 8; ++i)
#pragma unroll
                for (int c = 0; c < 8; ++c)
                    a[i][c] += xr[i] * wc[c];
        }
        const float4 b0 = *(const float4*)(bp + j);
        const float4 b1v = *(const float4*)(bp + j + 4);
        const float bb[8] = {b0.x, b0.y, b0.z, b0.w, b1v.x, b1v.y, b1v.z, b1v.w};
#pragma unroll
        for (int i = 0; i < 8; ++i) {
            const size_t row = r0 + rg * 8 + i;
            if (row < NN) {
                float* orow = out + row * 349;
#pragma unroll
                for (int c = 0; c < 8; ++c) {
                    int jj = j + c;
                    if (jj < 349) orow[jj] = a[i][c] + bb[c];
                }
            }
        }
    }
}

extern "C" void kernel_launch(void* const* d_in, const int* in_sizes, int n_in,
                              void* d_out, int out_size, void* d_ws, size_t ws_size,
                              hipStream_t stream)
{
    (void)in_sizes; (void)n_in; (void)out_size; (void)ws_size;
    const float* xp = (const float*)d_in[0];
    const float* xa = (const float*)d_in[1];
    const int* eic = (const int*)d_in[2];
    const int* eiw = (const int*)d_in[3];
    const int* eiwb = (const int*)d_in[4];
    auto Wl = [&](int l, int r) { return (const float*)d_in[5 + (l * 3 + r) * 4 + 0]; };
    auto As = [&](int l, int r) { return (const float*)d_in[5 + (l * 3 + r) * 4 + 1]; };
    auto Ad = [&](int l, int r) { return (const float*)d_in[5 + (l * 3 + r) * 4 + 2]; };
    auto Bs = [&](int l, int r) { return (const float*)d_in[5 + (l * 3 + r) * 4 + 3]; };
    const float* linW = (const float*)d_in[29];
    const float* linb = (const float*)d_in[30];

    char* wsp = (char*)d_ws;
    auto carve = [&](size_t bytes) -> void* {
        void* p = (void*)wsp;
        wsp += (bytes + 255) & ~(size_t)255;
        return p;
    };
    float* Hs = (float*)carve((size_t)NN * 128 * 4);   // per-relation transformed feats
    float* P1 = (float*)carve((size_t)NN * 128 * 4);   // paper layer0 out
    float* A1 = (float*)carve((size_t)NN * 128 * 4);   // author layer0 out
    float* P2 = (float*)carve((size_t)NN * 128 * 4);   // paper layer1 out
    // one contiguous carve for all 3 degree arrays so one exact-size memset
    // zeroes everything
    int* deg = (int*)carve((size_t)NN * 3 * 4);
    int* deg_c = deg, *deg_w = deg + NN, *deg_wb = deg + 2 * NN;
    int* bkt_c = (int*)carve((size_t)NN * CAP * 4);
    int* bkt_w = (int*)carve((size_t)NN * CAP * 4);
    int* bkt_wb = (int*)carve((size_t)NN * CAP * 4);
    float* aS = (float*)carve((size_t)NN * 4 * 4);
    float* aD = (float*)carve((size_t)NN * 4 * 4);
    float* aX = (float*)carve((size_t)NN * 4 * 4);     // shared sink (never read)
    float* Wp = (float*)carve((size_t)128 * 352 * 4);
    float* bp = (float*)carve((size_t)352 * 4);
    float* Wf = (float*)carve((size_t)128 * 4 * 4);    // att-folded dst-side W

    dim3 blk(256);
    const int gG = NN / 32;             // 3125
    const int gE = (EE + 255) / 256;    // 977
    const int gA = NN * 32 / 256;       // 12500
    const int gO = (NN + 127) / 128;    // 782

    // ---- bucket build (edge structure is layer-invariant) ----
    hipMemsetAsync(deg, 0, (size_t)NN * 3 * 4, stream);
    fill_buckets<<<gE, blk, 0, stream>>>(eic, deg_c, bkt_c);
    fill_buckets<<<gE, blk, 0, stream>>>(eiw, deg_w, bkt_w);
    fill_buckets<<<gE, blk, 0, stream>>>(eiwb, deg_wb, bkt_wb);

    // ---- layer 0: written_by (paper -> author) ----
    gemm_att<<<gG, blk, 0, stream>>>(xp, Wl(0, 2), As(0, 2), Ad(0, 2), Hs, aS, aX);
    fold_w<<<2, blk, 0, stream>>>(Wl(0, 2), Ad(0, 2), Wf);
    gemv_att<<<gA, blk, 0, stream>>>(xa, Wf, aD);
    aggregate<<<gA, blk, 0, stream>>>(deg_wb, bkt_wb, aS, aD, Hs, A1, 0, Bs(0, 2), nullptr, 1);

    // ---- layer 0: cites (paper -> paper) ----
    gemm_att<<<gG, blk, 0, stream>>>(xp, Wl(0, 0), As(0, 0), Ad(0, 0), Hs, aS, aD);
    aggregate<<<gA, blk, 0, stream>>>(deg_c, bkt_c, aS, aD, Hs, P1, 0, nullptr, nullptr, 0);

    // ---- layer 0: writes (author -> paper), fuse biases + act ----
    gemm_att<<<gG, blk, 0, stream>>>(xa, Wl(0, 1), As(0, 1), Ad(0, 1), Hs, aS, aX);
    fold_w<<<2, blk, 0, stream>>>(Wl(0, 1), Ad(0, 1), Wf);
    gemv_att<<<gA, blk, 0, stream>>>(xp, Wf, aD);
    aggregate<<<gA, blk, 0, stream>>>(deg_w, bkt_w, aS, aD, Hs, P1, 1, Bs(0, 0), Bs(0, 1), 1);

    // ---- layer 1 (author output is dead code -> skip written_by) ----
    gemm_att<<<gG, blk, 0, stream>>>(P1, Wl(1, 0), As(1, 0), Ad(1, 0), Hs, aS, aD);
    aggregate<<<gA, blk, 0, stream>>>(deg_c, bkt_c, aS, aD, Hs, P2, 0, nullptr, nullptr, 0);

    gemm_att<<<gG, blk, 0, stream>>>(A1, Wl(1, 1), As(1, 1), Ad(1, 1), Hs, aS, aX);
    fold_w<<<2, blk, 0, stream>>>(Wl(1, 1), Ad(1, 1), Wf);
    gemv_att<<<gA, blk, 0, stream>>>(P1, Wf, aD);
    aggregate<<<gA, blk, 0, stream>>>(deg_w, bkt_w, aS, aD, Hs, P2, 1, Bs(1, 0), Bs(1, 1), 0);

    // ---- classifier head ----
    pad_w<<<176, blk, 0, stream>>>(linW, linb, Wp, bp);
    gemm_out<<<gO, blk, 0, stream>>>(P2, Wp, bp, (float*)d_out);
}

// Round 3
// 1092.306 us; speedup vs baseline: 1.0077x; 1.0077x over previous
//
#include <hip/hip_runtime.h>

#define NN 100000
#define EE 250000
#define CAP 32

typedef unsigned int u32;

// H = X @ W  (X: [NN,128] f32, W: [128,128] f32), plus attention scalars
// aS[n][h] = sum_c H[n][h*32+c]*atts[h][c], same for aD.
__global__ __launch_bounds__(256) void gemm_att(
    const float* __restrict__ X, const float* __restrict__ W,
    const float* __restrict__ atts, const float* __restrict__ attd,
    float* __restrict__ H, float* __restrict__ aS, float* __restrict__ aD)
{
    __shared__ float sW[64 * 128];    // 32 KB (half of W at a time)
    __shared__ float sXT[128 * 32];   // 16 KB transposed: [k][row]
    const int tid = threadIdx.x;
    const size_t r0 = (size_t)blockIdx.x * 32;

    {   // stage X tile (32 rows x 128) transposed
        int rl = tid & 31, kg = tid >> 5;   // kg 0..7
        const float4* Xr = (const float4*)(X + (r0 + rl) * 128);
#pragma unroll
        for (int t = 0; t < 4; ++t) {
            float4 u = Xr[kg * 4 + t];
            int k = kg * 16 + t * 4;
            sXT[(k + 0) * 32 + rl] = u.x;
            sXT[(k + 1) * 32 + rl] = u.y;
            sXT[(k + 2) * 32 + rl] = u.z;
            sXT[(k + 3) * 32 + rl] = u.w;
        }
    }

    const int jg = tid & 31;   // 4 cols: jg*4 .. jg*4+3
    const int rg = tid >> 5;   // 4 rows: rg*4 .. rg*4+3
    float acc[4][4] = {};

    for (int kh = 0; kh < 2; ++kh) {
        __syncthreads();
        const float4* Wu = (const float4*)(W + kh * 64 * 128);
        float4* sWv = (float4*)sW;
#pragma unroll
        for (int t = 0; t < 8; ++t)
            sWv[tid + 256 * t] = Wu[tid + 256 * t];
        __syncthreads();
#pragma unroll 4
        for (int k = 0; k < 64; ++k) {
            const float4 w = ((const float4*)sW)[k * 32 + jg];
            const int kk = kh * 64 + k;
            const float4 x = ((const float4*)sXT)[kk * 8 + rg];  // rows rg*4..+3
            acc[0][0] += w.x * x.x; acc[0][1] += w.y * x.x; acc[0][2] += w.z * x.x; acc[0][3] += w.w * x.x;
            acc[1][0] += w.x * x.y; acc[1][1] += w.y * x.y; acc[1][2] += w.z * x.y; acc[1][3] += w.w * x.y;
            acc[2][0] += w.x * x.z; acc[2][1] += w.y * x.z; acc[2][2] += w.z * x.z; acc[2][3] += w.w * x.z;
            acc[3][0] += w.x * x.w; acc[3][1] += w.y * x.w; acc[3][2] += w.z * x.w; acc[3][3] += w.w * x.w;
        }
    }

    const float4 sv = ((const float4*)atts)[jg];   // atts[jg*4 .. +3]
    const float4 dv = ((const float4*)attd)[jg];
    const int h = jg >> 3;                          // head = (jg*4)>>5

#pragma unroll
    for (int i = 0; i < 4; ++i) {
        const size_t row = r0 + rg * 4 + i;
        if (H)
            ((float4*)H)[row * 32 + jg] = make_float4(acc[i][0], acc[i][1], acc[i][2], acc[i][3]);
        float ps = acc[i][0] * sv.x + acc[i][1] * sv.y + acc[i][2] * sv.z + acc[i][3] * sv.w;
        float pd = acc[i][0] * dv.x + acc[i][1] * dv.y + acc[i][2] * dv.z + acc[i][3] * dv.w;
        // reduce across 8 consecutive lanes sharing (row, head)
        ps += __shfl_xor(ps, 1); ps += __shfl_xor(ps, 2); ps += __shfl_xor(ps, 4);
        pd += __shfl_xor(pd, 1); pd += __shfl_xor(pd, 2); pd += __shfl_xor(pd, 4);
        if ((jg & 7) == 0) {
            aS[row * 4 + h] = ps;
            aD[row * 4 + h] = pd;
        }
    }
}

// Wf[k][h] = sum_c W[k][h*32+c] * att[h][c]   (fold attention vector into W)
__global__ __launch_bounds__(256) void fold_w(
    const float* __restrict__ W, const float* __restrict__ att,
    float* __restrict__ Wf)
{
    int i = blockIdx.x * 256 + threadIdx.x;
    if (i >= 512) return;
    int k = i >> 2, h = i & 3;
    float s = 0.f;
#pragma unroll
    for (int c = 0; c < 32; ++c)
        s += W[k * 128 + h * 32 + c] * att[h * 32 + c];
    Wf[k * 4 + h] = s;
}

// aD[n][h] = sum_k X[n][k] * Wf[k][h] — dst-side attention scalar.
__global__ __launch_bounds__(256) void gemv_att(
    const float* __restrict__ X, const float* __restrict__ Wf,
    float* __restrict__ aD)
{
    __shared__ float sWf[512];
    const int tid = threadIdx.x;
    if (tid < 128)
        ((float4*)sWf)[tid] = ((const float4*)Wf)[tid];
    __syncthreads();
    const int t = blockIdx.x * 256 + tid;
    const int n = t >> 5, lane = t & 31;
    if (n >= NN) return;
    const float4 x = ((const float4*)X)[(size_t)n * 32 + lane];
    const float4 w0 = ((const float4*)sWf)[lane * 4 + 0];
    const float4 w1 = ((const float4*)sWf)[lane * 4 + 1];
    const float4 w2 = ((const float4*)sWf)[lane * 4 + 2];
    const float4 w3 = ((const float4*)sWf)[lane * 4 + 3];
    float p0 = x.x * w0.x + x.y * w1.x + x.z * w2.x + x.w * w3.x;
    float p1 = x.x * w0.y + x.y * w1.y + x.z * w2.y + x.w * w3.y;
    float p2 = x.x * w0.z + x.y * w1.z + x.z * w2.z + x.w * w3.z;
    float p3 = x.x * w0.w + x.y * w1.w + x.z * w2.w + x.w * w3.w;
#pragma unroll
    for (int off = 1; off < 32; off <<= 1) {
        p0 += __shfl_xor(p0, off);
        p1 += __shfl_xor(p1, off);
        p2 += __shfl_xor(p2, off);
        p3 += __shfl_xor(p3, off);
    }
    if (lane == 0)
        ((float4*)aD)[n] = make_float4(p0, p1, p2, p3);
}

// per-dst incoming-edge buckets (gather-based aggregation; no feature atomics)
__global__ __launch_bounds__(256) void fill_buckets(
    const int* __restrict__ ei, int* __restrict__ deg, int* __restrict__ bkt)
{
    int e = blockIdx.x * 256 + threadIdx.x;
    if (e >= EE) return;
    int s = ei[e], d = ei[EE + e];
    int slot = atomicAdd(&deg[d], 1);
    if (slot >= 0 && slot < CAP) bkt[(size_t)d * CAP + slot] = s;  // P(deg>32)~1e-19
}

// 32 lanes own one dst node: softmax over its in-edges + weighted gather.
// Mean degree is 2.5 (Poisson): first 4 edges are register-cached — one int4
// bucket load, then INDEPENDENT aS/Hs loads issued up-front (was two serial
// dependent-load passes per edge). Tail (P~11% g>4) falls back to old path.
// Summation order identical to before -> bit-identical output.
__global__ __launch_bounds__(256) void aggregate(
    const int* __restrict__ deg, const int* __restrict__ bkt,
    const float* __restrict__ aS, const float* __restrict__ aD,
    const float* __restrict__ Hs, float* __restrict__ out,
    int accumulate, const float* __restrict__ b1, const float* __restrict__ b2,
    int act)
{
    int t = blockIdx.x * 256 + threadIdx.x;
    int d = t >> 5, lane = t & 31;
    if (d >= NN) return;
    int g = deg[d]; if (g > CAP) g = CAP; if (g < 0) g = 0;
    const int h = lane >> 3;
    const float adh = aD[d * 4 + h];
    const int* mybkt = bkt + (size_t)d * CAP;

    // cached head (up to 4 edges)
    const int4 s4 = *(const int4*)mybkt;   // whole CAP=32 slot array exists; unused lanes ignored
    float e0 = 0.f, e1 = 0.f, e2 = 0.f, e3 = 0.f;
    float4 h0 = make_float4(0.f,0.f,0.f,0.f), h1 = h0, h2 = h0, h3 = h0;
    float m = -INFINITY;
    if (g > 0) { float e = aS[s4.x * 4 + h] + adh; e = e > 0.f ? e : 0.2f * e; e0 = e; m = fmaxf(m, e);
                 h0 = ((const float4*)Hs)[(size_t)s4.x * 32 + lane]; }
    if (g > 1) { float e = aS[s4.y * 4 + h] + adh; e = e > 0.f ? e : 0.2f * e; e1 = e; m = fmaxf(m, e);
                 h1 = ((const float4*)Hs)[(size_t)s4.y * 32 + lane]; }
    if (g > 2) { float e = aS[s4.z * 4 + h] + adh; e = e > 0.f ? e : 0.2f * e; e2 = e; m = fmaxf(m, e);
                 h2 = ((const float4*)Hs)[(size_t)s4.z * 32 + lane]; }
    if (g > 3) { float e = aS[s4.w * 4 + h] + adh; e = e > 0.f ? e : 0.2f * e; e3 = e; m = fmaxf(m, e);
                 h3 = ((const float4*)Hs)[(size_t)s4.w * 32 + lane]; }
    for (int j = 4; j < g; ++j) {                     // rare tail
        int s = mybkt[j];
        float e = aS[s * 4 + h] + adh;
        e = e > 0.f ? e : 0.2f * e;
        m = fmaxf(m, e);
    }

    float4 acc = make_float4(0.f, 0.f, 0.f, 0.f);
    float z = 0.f;
    if (g > 0) { float w = __expf(e0 - m); z += w;
                 acc.x += w * h0.x; acc.y += w * h0.y; acc.z += w * h0.z; acc.w += w * h0.w; }
    if (g > 1) { float w = __expf(e1 - m); z += w;
                 acc.x += w * h1.x; acc.y += w * h1.y; acc.z += w * h1.z; acc.w += w * h1.w; }
    if (g > 2) { float w = __expf(e2 - m); z += w;
                 acc.x += w * h2.x; acc.y += w * h2.y; acc.z += w * h2.z; acc.w += w * h2.w; }
    if (g > 3) { float w = __expf(e3 - m); z += w;
                 acc.x += w * h3.x; acc.y += w * h3.y; acc.z += w * h3.z; acc.w += w * h3.w; }
    for (int j = 4; j < g; ++j) {                     // rare tail
        int s = mybkt[j];
        float e = aS[s * 4 + h] + adh;
        e = e > 0.f ? e : 0.2f * e;
        float w = __expf(e - m);
        z += w;
        float4 hv = ((const float4*)Hs)[(size_t)s * 32 + lane];
        acc.x += w * hv.x; acc.y += w * hv.y; acc.z += w * hv.z; acc.w += w * hv.w;
    }
    float inv = 1.f / (z + 1e-16f);
    acc.x *= inv; acc.y *= inv; acc.z *= inv; acc.w *= inv;

    if (accumulate) {
        float4 p = ((const float4*)out)[(size_t)d * 32 + lane];
        acc.x += p.x; acc.y += p.y; acc.z += p.z; acc.w += p.w;
    }
    if (b1) {
        float4 bv = ((const float4*)b1)[lane];
        acc.x += bv.x; acc.y += bv.y; acc.z += bv.z; acc.w += bv.w;
    }
    if (b2) {
        float4 bv = ((const float4*)b2)[lane];
        acc.x += bv.x; acc.y += bv.y; acc.z += bv.z; acc.w += bv.w;
    }
    if (act) {
        acc.x = acc.x > 0.f ? acc.x : 0.01f * acc.x;
        acc.y = acc.y > 0.f ? acc.y : 0.01f * acc.y;
        acc.z = acc.z > 0.f ? acc.z : 0.01f * acc.z;
        acc.w = acc.w > 0.f ? acc.w : 0.01f * acc.w;
    }
    ((float4*)out)[(size_t)d * 32 + lane] = acc;
}

// pad lin_W [128,349] f32 -> f32 [128,352]; lin_b -> f32 [352]
__global__ __launch_bounds__(256) void pad_w(
    const float* __restrict__ Wl, const float* __restrict__ bl,
    float* __restrict__ Wp, float* __restrict__ bp)
{
    int i = blockIdx.x * 256 + threadIdx.x;
    if (i >= 128 * 352) return;
    int k = i / 352, j = i - k * 352;
    Wp[i] = (j < 349) ? Wl[k * 349 + j] : 0.0f;
    if (i < 352) bp[i] = (i < 349) ? bl[i] : 0.0f;
}

// out[100000,349] f32 = X[100000,128] f32 @ Wp[128,352] f32 + bp
// 128 rows/block, 8x8 register blocking, X^T staged in k-chunks of 64
// (32 KB LDS single buffer, restaged per (jt,kc)) -> ~4 blocks/CU resident
// (the R1 64KB version had OccupancyPercent 17 -> latency-bound at 215us).
__global__ __launch_bounds__(256) void gemm_out(
    const float* __restrict__ X, const float* __restrict__ Wp,
    const float* __restrict__ bp, float* __restrict__ out)
{
    __shared__ float sXT[64 * 128];   // [k-local][row], 32 KB
    const int tid = threadIdx.x;
    const size_t r0 = (size_t)blockIdx.x * 128;
    const int jg = tid & 15;    // 8 cols: j .. j+7
    const int rg = tid >> 4;    // 8 rows: rg*8 .. rg*8+7
    const int rl = tid & 127, sg = tid >> 7;   // staging coords
    const size_t srow = r0 + rl;
    const bool svalid = srow < NN;
    const float4* Xr = (const float4*)(X + srow * 128);

    for (int jt = 0; jt < 3; ++jt) {
        const int j = jt * 128 + jg * 8;
        float a[8][8] = {};
        for (int kc = 0; kc < 2; ++kc) {
            __syncthreads();   // previous reads of sXT done
            {
#pragma unroll
                for (int t = 0; t < 8; ++t) {
                    float4 u = svalid ? Xr[kc * 16 + sg * 8 + t]
                                      : make_float4(0.f, 0.f, 0.f, 0.f);
                    int k = (sg * 8 + t) * 4;   // 0..60 local
                    sXT[(k + 0) * 128 + rl] = u.x;
                    sXT[(k + 1) * 128 + rl] = u.y;
                    sXT[(k + 2) * 128 + rl] = u.z;
                    sXT[(k + 3) * 128 + rl] = u.w;
                }
            }
            __syncthreads();
            if (j < 352) {
                const float* Wk = Wp + (size_t)(kc * 64) * 352 + j;
#pragma unroll 4
                for (int k = 0; k < 64; ++k) {
                    const float4 x0 = ((const float4*)sXT)[k * 32 + rg * 2];
                    const float4 x1 = ((const float4*)sXT)[k * 32 + rg * 2 + 1];
                    const float4 w0 = *(const float4*)(Wk + (size_t)k * 352);
                    const float4 w1 = *(const float4*)(Wk + (size_t)k * 352 + 4);
                    const float xr[8] = {x0.x, x0.y, x0.z, x0.w, x1.x, x1.y, x1.z, x1.w};
                    const float wc[8] = {w0.x, w0.y, w0.z, w0.w, w1.x, w1.y, w1.z, w1.w};
#pragma unroll
                    for (int i = 0; i < 8; ++i)
#pragma unroll
                        for (int c = 0; c < 8; ++c)
                            a[i][c] += xr[i] * wc[c];
                }
            }
        }
        if (j < 352) {
            const float4 b0 = *(const float4*)(bp + j);
            const float4 b1v = *(const float4*)(bp + j + 4);
            const float bb[8] = {b0.x, b0.y, b0.z, b0.w, b1v.x, b1v.y, b1v.z, b1v.w};
#pragma unroll
            for (int i = 0; i < 8; ++i) {
                const size_t row = r0 + rg * 8 + i;
                if (row < NN) {
                    float* orow = out + row * 349;
#pragma unroll
                    for (int c = 0; c < 8; ++c) {
                        int jj = j + c;
                        if (jj < 349) orow[jj] = a[i][c] + bb[c];
                    }
                }
            }
        }
    }
}

extern "C" void kernel_launch(void* const* d_in, const int* in_sizes, int n_in,
                              void* d_out, int out_size, void* d_ws, size_t ws_size,
                              hipStream_t stream)
{
    (void)in_sizes; (void)n_in; (void)out_size; (void)ws_size;
    const float* xp = (const float*)d_in[0];
    const float* xa = (const float*)d_in[1];
    const int* eic = (const int*)d_in[2];
    const int* eiw = (const int*)d_in[3];
    const int* eiwb = (const int*)d_in[4];
    auto Wl = [&](int l, int r) { return (const float*)d_in[5 + (l * 3 + r) * 4 + 0]; };
    auto As = [&](int l, int r) { return (const float*)d_in[5 + (l * 3 + r) * 4 + 1]; };
    auto Ad = [&](int l, int r) { return (const float*)d_in[5 + (l * 3 + r) * 4 + 2]; };
    auto Bs = [&](int l, int r) { return (const float*)d_in[5 + (l * 3 + r) * 4 + 3]; };
    const float* linW = (const float*)d_in[29];
    const float* linb = (const float*)d_in[30];

    char* wsp = (char*)d_ws;
    auto carve = [&](size_t bytes) -> void* {
        void* p = (void*)wsp;
        wsp += (bytes + 255) & ~(size_t)255;
        return p;
    };
    float* Hs = (float*)carve((size_t)NN * 128 * 4);   // per-relation transformed feats
    float* P1 = (float*)carve((size_t)NN * 128 * 4);   // paper layer0 out
    float* A1 = (float*)carve((size_t)NN * 128 * 4);   // author layer0 out
    float* P2 = (float*)carve((size_t)NN * 128 * 4);   // paper layer1 out
    // one contiguous carve for all 3 degree arrays so one exact-size memset
    // zeroes everything
    int* deg = (int*)carve((size_t)NN * 3 * 4);
    int* deg_c = deg, *deg_w = deg + NN, *deg_wb = deg + 2 * NN;
    int* bkt_c = (int*)carve((size_t)NN * CAP * 4);
    int* bkt_w = (int*)carve((size_t)NN * CAP * 4);
    int* bkt_wb = (int*)carve((size_t)NN * CAP * 4);
    float* aS = (float*)carve((size_t)NN * 4 * 4);
    float* aD = (float*)carve((size_t)NN * 4 * 4);
    float* aX = (float*)carve((size_t)NN * 4 * 4);     // shared sink (never read)
    float* Wp = (float*)carve((size_t)128 * 352 * 4);
    float* bp = (float*)carve((size_t)352 * 4);
    float* Wf = (float*)carve((size_t)128 * 4 * 4);    // att-folded dst-side W

    dim3 blk(256);
    const int gG = NN / 32;             // 3125
    const int gE = (EE + 255) / 256;    // 977
    const int gA = NN * 32 / 256;       // 12500
    const int gO = (NN + 127) / 128;    // 782

    // ---- bucket build (edge structure is layer-invariant) ----
    hipMemsetAsync(deg, 0, (size_t)NN * 3 * 4, stream);
    fill_buckets<<<gE, blk, 0, stream>>>(eic, deg_c, bkt_c);
    fill_buckets<<<gE, blk, 0, stream>>>(eiw, deg_w, bkt_w);
    fill_buckets<<<gE, blk, 0, stream>>>(eiwb, deg_wb, bkt_wb);

    // ---- layer 0: written_by (paper -> author) ----
    gemm_att<<<gG, blk, 0, stream>>>(xp, Wl(0, 2), As(0, 2), Ad(0, 2), Hs, aS, aX);
    fold_w<<<2, blk, 0, stream>>>(Wl(0, 2), Ad(0, 2), Wf);
    gemv_att<<<gA, blk, 0, stream>>>(xa, Wf, aD);
    aggregate<<<gA, blk, 0, stream>>>(deg_wb, bkt_wb, aS, aD, Hs, A1, 0, Bs(0, 2), nullptr, 1);

    // ---- layer 0: cites (paper -> paper) ----
    gemm_att<<<gG, blk, 0, stream>>>(xp, Wl(0, 0), As(0, 0), Ad(0, 0), Hs, aS, aD);
    aggregate<<<gA, blk, 0, stream>>>(deg_c, bkt_c, aS, aD, Hs, P1, 0, nullptr, nullptr, 0);

    // ---- layer 0: writes (author -> paper), fuse biases + act ----
    gemm_att<<<gG, blk, 0, stream>>>(xa, Wl(0, 1), As(0, 1), Ad(0, 1), Hs, aS, aX);
    fold_w<<<2, blk, 0, stream>>>(Wl(0, 1), Ad(0, 1), Wf);
    gemv_att<<<gA, blk, 0, stream>>>(xp, Wf, aD);
    aggregate<<<gA, blk, 0, stream>>>(deg_w, bkt_w, aS, aD, Hs, P1, 1, Bs(0, 0), Bs(0, 1), 1);

    // ---- layer 1 (author output is dead code -> skip written_by) ----
    gemm_att<<<gG, blk, 0, stream>>>(P1, Wl(1, 0), As(1, 0), Ad(1, 0), Hs, aS, aD);
    aggregate<<<gA, blk, 0, stream>>>(deg_c, bkt_c, aS, aD, Hs, P2, 0, nullptr, nullptr, 0);

    gemm_att<<<gG, blk, 0, stream>>>(A1, Wl(1, 1), As(1, 1), Ad(1, 1), Hs, aS, aX);
    fold_w<<<2, blk, 0, stream>>>(Wl(1, 1), Ad(1, 1), Wf);
    gemv_att<<<gA, blk, 0, stream>>>(P1, Wf, aD);
    aggregate<<<gA, blk, 0, stream>>>(deg_w, bkt_w, aS, aD, Hs, P2, 1, Bs(1, 0), Bs(1, 1), 0);

    // ---- classifier head ----
    pad_w<<<176, blk, 0, stream>>>(linW, linb, Wp, bp);
    gemm_out<<<gO, blk, 0, stream>>>(P2, Wp, bp, (float*)d_out);
}

// Round 5
// 959.174 us; speedup vs baseline: 1.1475x; 1.1388x over previous
//
#include <hip/hip_runtime.h>

#define NN 100000
#define EE 250000
#define CAP 32

typedef unsigned int u32;

// H = X @ W  (X: [NN,128] f32, W: [128,128] f32), plus attention scalars
// aS[n][h] = sum_c H[n][h*32+c]*atts[h][c], same for aD.
__global__ __launch_bounds__(256) void gemm_att(
    const float* __restrict__ X, const float* __restrict__ W,
    const float* __restrict__ atts, const float* __restrict__ attd,
    float* __restrict__ H, float* __restrict__ aS, float* __restrict__ aD)
{
    __shared__ float sW[64 * 128];    // 32 KB (half of W at a time)
    __shared__ float sXT[128 * 32];   // 16 KB transposed: [k][row]
    const int tid = threadIdx.x;
    const size_t r0 = (size_t)blockIdx.x * 32;

    {   // stage X tile (32 rows x 128) transposed
        int rl = tid & 31, kg = tid >> 5;   // kg 0..7
        const float4* Xr = (const float4*)(X + (r0 + rl) * 128);
#pragma unroll
        for (int t = 0; t < 4; ++t) {
            float4 u = Xr[kg * 4 + t];
            int k = kg * 16 + t * 4;
            sXT[(k + 0) * 32 + rl] = u.x;
            sXT[(k + 1) * 32 + rl] = u.y;
            sXT[(k + 2) * 32 + rl] = u.z;
            sXT[(k + 3) * 32 + rl] = u.w;
        }
    }

    const int jg = tid & 31;   // 4 cols: jg*4 .. jg*4+3
    const int rg = tid >> 5;   // 4 rows: rg*4 .. rg*4+3
    float acc[4][4] = {};

    for (int kh = 0; kh < 2; ++kh) {
        __syncthreads();
        const float4* Wu = (const float4*)(W + kh * 64 * 128);
        float4* sWv = (float4*)sW;
#pragma unroll
        for (int t = 0; t < 8; ++t)
            sWv[tid + 256 * t] = Wu[tid + 256 * t];
        __syncthreads();
#pragma unroll 4
        for (int k = 0; k < 64; ++k) {
            const float4 w = ((const float4*)sW)[k * 32 + jg];
            const int kk = kh * 64 + k;
            const float4 x = ((const float4*)sXT)[kk * 8 + rg];  // rows rg*4..+3
            acc[0][0] += w.x * x.x; acc[0][1] += w.y * x.x; acc[0][2] += w.z * x.x; acc[0][3] += w.w * x.x;
            acc[1][0] += w.x * x.y; acc[1][1] += w.y * x.y; acc[1][2] += w.z * x.y; acc[1][3] += w.w * x.y;
            acc[2][0] += w.x * x.z; acc[2][1] += w.y * x.z; acc[2][2] += w.z * x.z; acc[2][3] += w.w * x.z;
            acc[3][0] += w.x * x.w; acc[3][1] += w.y * x.w; acc[3][2] += w.z * x.w; acc[3][3] += w.w * x.w;
        }
    }

    const float4 sv = ((const float4*)atts)[jg];   // atts[jg*4 .. +3]
    const float4 dv = ((const float4*)attd)[jg];
    const int h = jg >> 3;                          // head = (jg*4)>>5

#pragma unroll
    for (int i = 0; i < 4; ++i) {
        const size_t row = r0 + rg * 4 + i;
        if (H)
            ((float4*)H)[row * 32 + jg] = make_float4(acc[i][0], acc[i][1], acc[i][2], acc[i][3]);
        float ps = acc[i][0] * sv.x + acc[i][1] * sv.y + acc[i][2] * sv.z + acc[i][3] * sv.w;
        float pd = acc[i][0] * dv.x + acc[i][1] * dv.y + acc[i][2] * dv.z + acc[i][3] * dv.w;
        // reduce across 8 consecutive lanes sharing (row, head)
        ps += __shfl_xor(ps, 1); ps += __shfl_xor(ps, 2); ps += __shfl_xor(ps, 4);
        pd += __shfl_xor(pd, 1); pd += __shfl_xor(pd, 2); pd += __shfl_xor(pd, 4);
        if ((jg & 7) == 0) {
            aS[row * 4 + h] = ps;
            aD[row * 4 + h] = pd;
        }
    }
}

// Wf[r][k][h] = sum_c Wr[k][h*32+c] * ar[h][c] for the 3 dst-side relations,
// all inputs are kernel args -> one up-front launch (was 3x 2-block launches).
__global__ __launch_bounds__(256) void fold_w3(
    const float* __restrict__ W0, const float* __restrict__ a0,
    const float* __restrict__ W1, const float* __restrict__ a1,
    const float* __restrict__ W2, const float* __restrict__ a2,
    float* __restrict__ Wf)   // [3][128][4]
{
    int i = blockIdx.x * 256 + threadIdx.x;
    if (i >= 1536) return;
    int r = i >> 9, j = i & 511;
    int k = j >> 2, h = j & 3;
    const float* W = (r == 0) ? W0 : (r == 1) ? W1 : W2;
    const float* a = (r == 0) ? a0 : (r == 1) ? a1 : a2;
    float s = 0.f;
#pragma unroll
    for (int c = 0; c < 32; ++c)
        s += W[k * 128 + h * 32 + c] * a[h * 32 + c];
    Wf[i] = s;
}

// aD[n][h] = sum_k X[n][k] * Wf[k][h] — dst-side attention scalar.
__global__ __launch_bounds__(256) void gemv_att(
    const float* __restrict__ X, const float* __restrict__ Wf,
    float* __restrict__ aD)
{
    __shared__ float sWf[512];
    const int tid = threadIdx.x;
    if (tid < 128)
        ((float4*)sWf)[tid] = ((const float4*)Wf)[tid];
    __syncthreads();
    const int t = blockIdx.x * 256 + tid;
    const int n = t >> 5, lane = t & 31;
    if (n >= NN) return;
    const float4 x = ((const float4*)X)[(size_t)n * 32 + lane];
    const float4 w0 = ((const float4*)sWf)[lane * 4 + 0];
    const float4 w1 = ((const float4*)sWf)[lane * 4 + 1];
    const float4 w2 = ((const float4*)sWf)[lane * 4 + 2];
    const float4 w3 = ((const float4*)sWf)[lane * 4 + 3];
    float p0 = x.x * w0.x + x.y * w1.x + x.z * w2.x + x.w * w3.x;
    float p1 = x.x * w0.y + x.y * w1.y + x.z * w2.y + x.w * w3.y;
    float p2 = x.x * w0.z + x.y * w1.z + x.z * w2.z + x.w * w3.z;
    float p3 = x.x * w0.w + x.y * w1.w + x.z * w2.w + x.w * w3.w;
#pragma unroll
    for (int off = 1; off < 32; off <<= 1) {
        p0 += __shfl_xor(p0, off);
        p1 += __shfl_xor(p1, off);
        p2 += __shfl_xor(p2, off);
        p3 += __shfl_xor(p3, off);
    }
    if (lane == 0)
        ((float4*)aD)[n] = make_float4(p0, p1, p2, p3);
}

// per-dst incoming-edge buckets (gather-based aggregation; no feature atomics)
__global__ __launch_bounds__(256) void fill_buckets(
    const int* __restrict__ ei, int* __restrict__ deg, int* __restrict__ bkt)
{
    int e = blockIdx.x * 256 + threadIdx.x;
    if (e >= EE) return;
    int s = ei[e], d = ei[EE + e];
    int slot = atomicAdd(&deg[d], 1);
    if (slot >= 0 && slot < CAP) bkt[(size_t)d * CAP + slot] = s;  // P(deg>32)~1e-19
}

// 32 lanes own one dst node: softmax over its in-edges + weighted gather.
// Head of 8 edges fully register-resident (P(g>8)~0.2% for Poisson 2.5):
// pass 1 loads aS for 8 clamped indices UNCONDITIONALLY (index 0 when j>=g,
// always valid) -> 8 independent loads, no bkt->aS dependent chain; pass 2
// issues Hs gathers from register-held indices. Op order j-ascending ->
// bit-identical to previous rounds.
__global__ __launch_bounds__(256) void aggregate(
    const int* __restrict__ deg, const int* __restrict__ bkt,
    const float* __restrict__ aS, const float* __restrict__ aD,
    const float* __restrict__ Hs, float* __restrict__ out,
    int accumulate, const float* __restrict__ b1, const float* __restrict__ b2,
    int act)
{
    int t = blockIdx.x * 256 + threadIdx.x;
    int d = t >> 5, lane = t & 31;
    if (d >= NN) return;
    int g = deg[d]; if (g > CAP) g = CAP; if (g < 0) g = 0;
    const int h = lane >> 3;
    const float adh = aD[d * 4 + h];
    const int* mybkt = bkt + (size_t)d * CAP;

    const int4 sa = *(const int4*)mybkt;        // slots 0..3
    const int4 sb = *(const int4*)(mybkt + 4);  // slots 4..7
    int sidx[8] = {sa.x, sa.y, sa.z, sa.w, sb.x, sb.y, sb.z, sb.w};
#pragma unroll
    for (int j = 0; j < 8; ++j)
        sidx[j] = (j < g) ? sidx[j] : 0;        // clamp -> loads always valid

    float e[8];
#pragma unroll
    for (int j = 0; j < 8; ++j) {               // 8 independent aS loads
        float ev = aS[sidx[j] * 4 + h] + adh;
        e[j] = ev > 0.f ? ev : 0.2f * ev;
    }
    float m = -INFINITY;
#pragma unroll
    for (int j = 0; j < 8; ++j)
        if (j < g) m = fmaxf(m, e[j]);
    for (int j = 8; j < g; ++j) {               // ultra-rare tail
        int s = mybkt[j];
        float ev = aS[s * 4 + h] + adh;
        ev = ev > 0.f ? ev : 0.2f * ev;
        m = fmaxf(m, ev);
    }

    float4 acc = make_float4(0.f, 0.f, 0.f, 0.f);
    float z = 0.f;
#pragma unroll
    for (int j = 0; j < 8; ++j) {
        if (j < g) {
            float w = __expf(e[j] - m);
            z += w;
            float4 hv = ((const float4*)Hs)[(size_t)sidx[j] * 32 + lane];
            acc.x += w * hv.x; acc.y += w * hv.y; acc.z += w * hv.z; acc.w += w * hv.w;
        }
    }
    for (int j = 8; j < g; ++j) {               // ultra-rare tail
        int s = mybkt[j];
        float ev = aS[s * 4 + h] + adh;
        ev = ev > 0.f ? ev : 0.2f * ev;
        float w = __expf(ev - m);
        z += w;
        float4 hv = ((const float4*)Hs)[(size_t)s * 32 + lane];
        acc.x += w * hv.x; acc.y += w * hv.y; acc.z += w * hv.z; acc.w += w * hv.w;
    }
    float inv = 1.f / (z + 1e-16f);
    acc.x *= inv; acc.y *= inv; acc.z *= inv; acc.w *= inv;

    if (accumulate) {
        float4 p = ((const float4*)out)[(size_t)d * 32 + lane];
        acc.x += p.x; acc.y += p.y; acc.z += p.z; acc.w += p.w;
    }
    if (b1) {
        float4 bv = ((const float4*)b1)[lane];
        acc.x += bv.x; acc.y += bv.y; acc.z += bv.z; acc.w += bv.w;
    }
    if (b2) {
        float4 bv = ((const float4*)b2)[lane];
        acc.x += bv.x; acc.y += bv.y; acc.z += bv.z; acc.w += bv.w;
    }
    if (act) {
        acc.x = acc.x > 0.f ? acc.x : 0.01f * acc.x;
        acc.y = acc.y > 0.f ? acc.y : 0.01f * acc.y;
        acc.z = acc.z > 0.f ? acc.z : 0.01f * acc.z;
        acc.w = acc.w > 0.f ? acc.w : 0.01f * acc.w;
    }
    ((float4*)out)[(size_t)d * 32 + lane] = acc;
}

// pad lin_W [128,349] f32 -> f32 [128,384]; lin_b -> f32 [384]
// (384 = 3 uniform 128-col j-tiles for gemm_out)
__global__ __launch_bounds__(256) void pad_w(
    const float* __restrict__ Wl, const float* __restrict__ bl,
    float* __restrict__ Wp, float* __restrict__ bp)
{
    int i = blockIdx.x * 256 + threadIdx.x;
    if (i >= 128 * 384) return;
    int k = i / 384, j = i - k * 384;
    Wp[i] = (j < 349) ? Wl[k * 349 + j] : 0.0f;
    if (i < 384) bp[i] = (i < 349) ? bl[i] : 0.0f;
}

// out[100000,349] f32 = X[100000,128] f32 @ Wp[128,384] f32 + bp
// Structured EXACTLY like gemm_att (the empirically fastest f32 GEMM here:
// ~35-45us per 128-col pass): 32-row blocks, X^T staged once in 16 KB,
// W j-tile staged per (jt,kh) in 32 KB LDS, 4x4 micro-tile. 48 KB LDS ->
// 3 blocks/CU. R1 (64KB LDS, occ 17%) and R2 (X restaged from HBM 3x,
// FETCH 77MB) both regressed; this keeps X staging single-shot and W in LDS.
__global__ __launch_bounds__(256) void gemm_out(
    const float* __restrict__ X, const float* __restrict__ Wp,
    const float* __restrict__ bp, float* __restrict__ out)
{
    __shared__ float sW[64 * 128];    // 32 KB: [k-local][tile-col]
    __shared__ float sXT[128 * 32];   // 16 KB transposed: [k][row]
    const int tid = threadIdx.x;
    const size_t r0 = (size_t)blockIdx.x * 32;   // NN = 3125*32 exactly

    {   // stage X tile (32 rows x 128) transposed — identical to gemm_att
        int rl = tid & 31, kg = tid >> 5;
        const float4* Xr = (const float4*)(X + (r0 + rl) * 128);
#pragma unroll
        for (int t = 0; t < 4; ++t) {
            float4 u = Xr[kg * 4 + t];
            int k = kg * 16 + t * 4;
            sXT[(k + 0) * 32 + rl] = u.x;
            sXT[(k + 1) * 32 + rl] = u.y;
            sXT[(k + 2) * 32 + rl] = u.z;
            sXT[(k + 3) * 32 + rl] = u.w;
        }
    }

    const int jg = tid & 31;   // 4 cols within tile
    const int rg = tid >> 5;   // 4 rows

    for (int jt = 0; jt < 3; ++jt) {
        float acc[4][4] = {};
        for (int kh = 0; kh < 2; ++kh) {
            __syncthreads();   // prior sW reads (and jt=0: sXT stage) done
            {   // stage W[kh*64 .. +63][jt*128 .. +127] -> sW[64][128]
                const float4* Wu = (const float4*)Wp;   // row stride 96 f4
                float4* sWv = (float4*)sW;
#pragma unroll
                for (int t = 0; t < 8; ++t) {
                    int f = tid + 256 * t;          // 0..2047
                    int r = f >> 5, c4 = f & 31;
                    sWv[f] = Wu[(size_t)(kh * 64 + r) * 96 + jt * 32 + c4];
                }
            }
            __syncthreads();
#pragma unroll 4
            for (int k = 0; k < 64; ++k) {
                const float4 w = ((const float4*)sW)[k * 32 + jg];
                const float4 x = ((const float4*)sXT)[(kh * 64 + k) * 8 + rg];
                acc[0][0] += w.x * x.x; acc[0][1] += w.y * x.x; acc[0][2] += w.z * x.x; acc[0][3] += w.w * x.x;
                acc[1][0] += w.x * x.y; acc[1][1] += w.y * x.y; acc[1][2] += w.z * x.y; acc[1][3] += w.w * x.y;
                acc[2][0] += w.x * x.z; acc[2][1] += w.y * x.z; acc[2][2] += w.z * x.z; acc[2][3] += w.w * x.z;
                acc[3][0] += w.x * x.w; acc[3][1] += w.y * x.w; acc[3][2] += w.z * x.w; acc[3][3] += w.w * x.w;
            }
        }
        const int j = jt * 128 + jg * 4;
        const float4 bb = *(const float4*)(bp + j);
#pragma unroll
        for (int i = 0; i < 4; ++i) {
            const size_t row = r0 + rg * 4 + i;
            float* orow = out + row * 349;
            if (j + 0 < 349) orow[j + 0] = acc[i][0] + bb.x;
            if (j + 1 < 349) orow[j + 1] = acc[i][1] + bb.y;
            if (j + 2 < 349) orow[j + 2] = acc[i][2] + bb.z;
            if (j + 3 < 349) orow[j + 3] = acc[i][3] + bb.w;
        }
    }
}

extern "C" void kernel_launch(void* const* d_in, const int* in_sizes, int n_in,
                              void* d_out, int out_size, void* d_ws, size_t ws_size,
                              hipStream_t stream)
{
    (void)in_sizes; (void)n_in; (void)out_size; (void)ws_size;
    const float* xp = (const float*)d_in[0];
    const float* xa = (const float*)d_in[1];
    const int* eic = (const int*)d_in[2];
    const int* eiw = (const int*)d_in[3];
    const int* eiwb = (const int*)d_in[4];
    auto Wl = [&](int l, int r) { return (const float*)d_in[5 + (l * 3 + r) * 4 + 0]; };
    auto As = [&](int l, int r) { return (const float*)d_in[5 + (l * 3 + r) * 4 + 1]; };
    auto Ad = [&](int l, int r) { return (const float*)d_in[5 + (l * 3 + r) * 4 + 2]; };
    auto Bs = [&](int l, int r) { return (const float*)d_in[5 + (l * 3 + r) * 4 + 3]; };
    const float* linW = (const float*)d_in[29];
    const float* linb = (const float*)d_in[30];

    char* wsp = (char*)d_ws;
    auto carve = [&](size_t bytes) -> void* {
        void* p = (void*)wsp;
        wsp += (bytes + 255) & ~(size_t)255;
        return p;
    };
    float* Hs = (float*)carve((size_t)NN * 128 * 4);   // per-relation transformed feats
    float* P1 = (float*)carve((size_t)NN * 128 * 4);   // paper layer0 out
    float* A1 = (float*)carve((size_t)NN * 128 * 4);   // author layer0 out
    float* P2 = (float*)carve((size_t)NN * 128 * 4);   // paper layer1 out
    // one contiguous carve for all 3 degree arrays so one exact-size memset
    // zeroes everything
    int* deg = (int*)carve((size_t)NN * 3 * 4);
    int* deg_c = deg, *deg_w = deg + NN, *deg_wb = deg + 2 * NN;
    int* bkt_c = (int*)carve((size_t)NN * CAP * 4);
    int* bkt_w = (int*)carve((size_t)NN * CAP * 4);
    int* bkt_wb = (int*)carve((size_t)NN * CAP * 4);
    float* aS = (float*)carve((size_t)NN * 4 * 4);
    float* aD = (float*)carve((size_t)NN * 4 * 4);
    float* aX = (float*)carve((size_t)NN * 4 * 4);     // shared sink (never read)
    float* Wp = (float*)carve((size_t)128 * 384 * 4);
    float* bp = (float*)carve((size_t)384 * 4);
    float* Wf = (float*)carve((size_t)3 * 512 * 4);    // att-folded dst-side W x3

    dim3 blk(256);
    const int gG = NN / 32;             // 3125
    const int gE = (EE + 255) / 256;    // 977
    const int gA = NN * 32 / 256;       // 12500

    // ---- bucket build + all weight folds (layer-invariant / input-only) ----
    hipMemsetAsync(deg, 0, (size_t)NN * 3 * 4, stream);
    fill_buckets<<<gE, blk, 0, stream>>>(eic, deg_c, bkt_c);
    fill_buckets<<<gE, blk, 0, stream>>>(eiw, deg_w, bkt_w);
    fill_buckets<<<gE, blk, 0, stream>>>(eiwb, deg_wb, bkt_wb);
    fold_w3<<<6, blk, 0, stream>>>(Wl(0, 2), Ad(0, 2), Wl(0, 1), Ad(0, 1),
                                   Wl(1, 1), Ad(1, 1), Wf);

    // ---- layer 0: written_by (paper -> author) ----
    gemm_att<<<gG, blk, 0, stream>>>(xp, Wl(0, 2), As(0, 2), Ad(0, 2), Hs, aS, aX);
    gemv_att<<<gA, blk, 0, stream>>>(xa, Wf + 0 * 512, aD);
    aggregate<<<gA, blk, 0, stream>>>(deg_wb, bkt_wb, aS, aD, Hs, A1, 0, Bs(0, 2), nullptr, 1);

    // ---- layer 0: cites (paper -> paper) ----
    gemm_att<<<gG, blk, 0, stream>>>(xp, Wl(0, 0), As(0, 0), Ad(0, 0), Hs, aS, aD);
    aggregate<<<gA, blk, 0, stream>>>(deg_c, bkt_c, aS, aD, Hs, P1, 0, nullptr, nullptr, 0);

    // ---- layer 0: writes (author -> paper), fuse biases + act ----
    gemm_att<<<gG, blk, 0, stream>>>(xa, Wl(0, 1), As(0, 1), Ad(0, 1), Hs, aS, aX);
    gemv_att<<<gA, blk, 0, stream>>>(xp, Wf + 1 * 512, aD);
    aggregate<<<gA, blk, 0, stream>>>(deg_w, bkt_w, aS, aD, Hs, P1, 1, Bs(0, 0), Bs(0, 1), 1);

    // ---- layer 1 (author output is dead code -> skip written_by) ----
    gemm_att<<<gG, blk, 0, stream>>>(P1, Wl(1, 0), As(1, 0), Ad(1, 0), Hs, aS, aD);
    aggregate<<<gA, blk, 0, stream>>>(deg_c, bkt_c, aS, aD, Hs, P2, 0, nullptr, nullptr, 0);

    gemm_att<<<gG, blk, 0, stream>>>(A1, Wl(1, 1), As(1, 1), Ad(1, 1), Hs, aS, aX);
    gemv_att<<<gA, blk, 0, stream>>>(P1, Wf + 2 * 512, aD);
    aggregate<<<gA, blk, 0, stream>>>(deg_w, bkt_w, aS, aD, Hs, P2, 1, Bs(1, 0), Bs(1, 1), 0);

    // ---- classifier head ----
    pad_w<<<192, blk, 0, stream>>>(linW, linb, Wp, bp);
    gemm_out<<<gG, blk, 0, stream>>>(P2, Wp, bp, (float*)d_out);
}

// Round 6
// 957.992 us; speedup vs baseline: 1.1490x; 1.0012x over previous
//
#include <hip/hip_runtime.h>

#define NN 100000
#define EE 250000
#define CAP 32

typedef unsigned int u32;
typedef unsigned short ushort;
typedef __attribute__((ext_vector_type(8))) short bf16x8;
typedef __attribute__((ext_vector_type(4))) float f32x4;

__device__ __forceinline__ ushort f2bf(float x) {   // f32 -> bf16 RNE
    u32 u = __float_as_uint(x);
    return (ushort)((u + 0x7fffu + ((u >> 16) & 1u)) >> 16);
}
__device__ __forceinline__ float bf2f(ushort h) {
    return __uint_as_float(((u32)h) << 16);
}

// H = X @ W  (X: [NN,128] f32, W: [128,128] f32), plus attention scalars
// aS[n][h] = sum_c H[n][h*32+c]*atts[h][c], same for aD.
__global__ __launch_bounds__(256) void gemm_att(
    const float* __restrict__ X, const float* __restrict__ W,
    const float* __restrict__ atts, const float* __restrict__ attd,
    float* __restrict__ H, float* __restrict__ aS, float* __restrict__ aD)
{
    __shared__ float sW[64 * 128];    // 32 KB (half of W at a time)
    __shared__ float sXT[128 * 32];   // 16 KB transposed: [k][row]
    const int tid = threadIdx.x;
    const size_t r0 = (size_t)blockIdx.x * 32;

    {   // stage X tile (32 rows x 128) transposed
        int rl = tid & 31, kg = tid >> 5;   // kg 0..7
        const float4* Xr = (const float4*)(X + (r0 + rl) * 128);
#pragma unroll
        for (int t = 0; t < 4; ++t) {
            float4 u = Xr[kg * 4 + t];
            int k = kg * 16 + t * 4;
            sXT[(k + 0) * 32 + rl] = u.x;
            sXT[(k + 1) * 32 + rl] = u.y;
            sXT[(k + 2) * 32 + rl] = u.z;
            sXT[(k + 3) * 32 + rl] = u.w;
        }
    }

    const int jg = tid & 31;   // 4 cols: jg*4 .. jg*4+3
    const int rg = tid >> 5;   // 4 rows: rg*4 .. rg*4+3
    float acc[4][4] = {};

    for (int kh = 0; kh < 2; ++kh) {
        __syncthreads();
        const float4* Wu = (const float4*)(W + kh * 64 * 128);
        float4* sWv = (float4*)sW;
#pragma unroll
        for (int t = 0; t < 8; ++t)
            sWv[tid + 256 * t] = Wu[tid + 256 * t];
        __syncthreads();
#pragma unroll 4
        for (int k = 0; k < 64; ++k) {
            const float4 w = ((const float4*)sW)[k * 32 + jg];
            const int kk = kh * 64 + k;
            const float4 x = ((const float4*)sXT)[kk * 8 + rg];  // rows rg*4..+3
            acc[0][0] += w.x * x.x; acc[0][1] += w.y * x.x; acc[0][2] += w.z * x.x; acc[0][3] += w.w * x.x;
            acc[1][0] += w.x * x.y; acc[1][1] += w.y * x.y; acc[1][2] += w.z * x.y; acc[1][3] += w.w * x.y;
            acc[2][0] += w.x * x.z; acc[2][1] += w.y * x.z; acc[2][2] += w.z * x.z; acc[2][3] += w.w * x.z;
            acc[3][0] += w.x * x.w; acc[3][1] += w.y * x.w; acc[3][2] += w.z * x.w; acc[3][3] += w.w * x.w;
        }
    }

    const float4 sv = ((const float4*)atts)[jg];   // atts[jg*4 .. +3]
    const float4 dv = ((const float4*)attd)[jg];
    const int h = jg >> 3;                          // head = (jg*4)>>5

#pragma unroll
    for (int i = 0; i < 4; ++i) {
        const size_t row = r0 + rg * 4 + i;
        if (H)
            ((float4*)H)[row * 32 + jg] = make_float4(acc[i][0], acc[i][1], acc[i][2], acc[i][3]);
        float ps = acc[i][0] * sv.x + acc[i][1] * sv.y + acc[i][2] * sv.z + acc[i][3] * sv.w;
        float pd = acc[i][0] * dv.x + acc[i][1] * dv.y + acc[i][2] * dv.z + acc[i][3] * dv.w;
        // reduce across 8 consecutive lanes sharing (row, head)
        ps += __shfl_xor(ps, 1); ps += __shfl_xor(ps, 2); ps += __shfl_xor(ps, 4);
        pd += __shfl_xor(pd, 1); pd += __shfl_xor(pd, 2); pd += __shfl_xor(pd, 4);
        if ((jg & 7) == 0) {
            aS[row * 4 + h] = ps;
            aD[row * 4 + h] = pd;
        }
    }
}

// Wf[r][k][h] = sum_c Wr[k][h*32+c] * ar[h][c] for the 3 dst-side relations,
// all inputs are kernel args -> one up-front launch (was 3x 2-block launches).
__global__ __launch_bounds__(256) void fold_w3(
    const float* __restrict__ W0, const float* __restrict__ a0,
    const float* __restrict__ W1, const float* __restrict__ a1,
    const float* __restrict__ W2, const float* __restrict__ a2,
    float* __restrict__ Wf)   // [3][128][4]
{
    int i = blockIdx.x * 256 + threadIdx.x;
    if (i >= 1536) return;
    int r = i >> 9, j = i & 511;
    int k = j >> 2, h = j & 3;
    const float* W = (r == 0) ? W0 : (r == 1) ? W1 : W2;
    const float* a = (r == 0) ? a0 : (r == 1) ? a1 : a2;
    float s = 0.f;
#pragma unroll
    for (int c = 0; c < 32; ++c)
        s += W[k * 128 + h * 32 + c] * a[h * 32 + c];
    Wf[i] = s;
}

// aD[n][h] = sum_k X[n][k] * Wf[k][h] — dst-side attention scalar.
__global__ __launch_bounds__(256) void gemv_att(
    const float* __restrict__ X, const float* __restrict__ Wf,
    float* __restrict__ aD)
{
    __shared__ float sWf[512];
    const int tid = threadIdx.x;
    if (tid < 128)
        ((float4*)sWf)[tid] = ((const float4*)Wf)[tid];
    __syncthreads();
    const int t = blockIdx.x * 256 + tid;
    const int n = t >> 5, lane = t & 31;
    if (n >= NN) return;
    const float4 x = ((const float4*)X)[(size_t)n * 32 + lane];
    const float4 w0 = ((const float4*)sWf)[lane * 4 + 0];
    const float4 w1 = ((const float4*)sWf)[lane * 4 + 1];
    const float4 w2 = ((const float4*)sWf)[lane * 4 + 2];
    const float4 w3 = ((const float4*)sWf)[lane * 4 + 3];
    float p0 = x.x * w0.x + x.y * w1.x + x.z * w2.x + x.w * w3.x;
    float p1 = x.x * w0.y + x.y * w1.y + x.z * w2.y + x.w * w3.y;
    float p2 = x.x * w0.z + x.y * w1.z + x.z * w2.z + x.w * w3.z;
    float p3 = x.x * w0.w + x.y * w1.w + x.z * w2.w + x.w * w3.w;
#pragma unroll
    for (int off = 1; off < 32; off <<= 1) {
        p0 += __shfl_xor(p0, off);
        p1 += __shfl_xor(p1, off);
        p2 += __shfl_xor(p2, off);
        p3 += __shfl_xor(p3, off);
    }
    if (lane == 0)
        ((float4*)aD)[n] = make_float4(p0, p1, p2, p3);
}

// per-dst incoming-edge buckets (gather-based aggregation; no feature atomics)
__global__ __launch_bounds__(256) void fill_buckets(
    const int* __restrict__ ei, int* __restrict__ deg, int* __restrict__ bkt)
{
    int e = blockIdx.x * 256 + threadIdx.x;
    if (e >= EE) return;
    int s = ei[e], d = ei[EE + e];
    int slot = atomicAdd(&deg[d], 1);
    if (slot >= 0 && slot < CAP) bkt[(size_t)d * CAP + slot] = s;  // P(deg>32)~1e-19
}

// 32 lanes own one dst node: softmax over its in-edges + weighted gather.
// Head of 8 edges fully register-resident (P(g>8)~0.2% for Poisson 2.5).
__global__ __launch_bounds__(256) void aggregate(
    const int* __restrict__ deg, const int* __restrict__ bkt,
    const float* __restrict__ aS, const float* __restrict__ aD,
    const float* __restrict__ Hs, float* __restrict__ out,
    int accumulate, const float* __restrict__ b1, const float* __restrict__ b2,
    int act)
{
    int t = blockIdx.x * 256 + threadIdx.x;
    int d = t >> 5, lane = t & 31;
    if (d >= NN) return;
    int g = deg[d]; if (g > CAP) g = CAP; if (g < 0) g = 0;
    const int h = lane >> 3;
    const float adh = aD[d * 4 + h];
    const int* mybkt = bkt + (size_t)d * CAP;

    const int4 sa = *(const int4*)mybkt;        // slots 0..3
    const int4 sb = *(const int4*)(mybkt + 4);  // slots 4..7
    int sidx[8] = {sa.x, sa.y, sa.z, sa.w, sb.x, sb.y, sb.z, sb.w};
#pragma unroll
    for (int j = 0; j < 8; ++j)
        sidx[j] = (j < g) ? sidx[j] : 0;        // clamp -> loads always valid

    float e[8];
#pragma unroll
    for (int j = 0; j < 8; ++j) {               // 8 independent aS loads
        float ev = aS[sidx[j] * 4 + h] + adh;
        e[j] = ev > 0.f ? ev : 0.2f * ev;
    }
    float m = -INFINITY;
#pragma unroll
    for (int j = 0; j < 8; ++j)
        if (j < g) m = fmaxf(m, e[j]);
    for (int j = 8; j < g; ++j) {               // ultra-rare tail
        int s = mybkt[j];
        float ev = aS[s * 4 + h] + adh;
        ev = ev > 0.f ? ev : 0.2f * ev;
        m = fmaxf(m, ev);
    }

    float4 acc = make_float4(0.f, 0.f, 0.f, 0.f);
    float z = 0.f;
#pragma unroll
    for (int j = 0; j < 8; ++j) {
        if (j < g) {
            float w = __expf(e[j] - m);
            z += w;
            float4 hv = ((const float4*)Hs)[(size_t)sidx[j] * 32 + lane];
            acc.x += w * hv.x; acc.y += w * hv.y; acc.z += w * hv.z; acc.w += w * hv.w;
        }
    }
    for (int j = 8; j < g; ++j) {               // ultra-rare tail
        int s = mybkt[j];
        float ev = aS[s * 4 + h] + adh;
        ev = ev > 0.f ? ev : 0.2f * ev;
        float w = __expf(ev - m);
        z += w;
        float4 hv = ((const float4*)Hs)[(size_t)s * 32 + lane];
        acc.x += w * hv.x; acc.y += w * hv.y; acc.z += w * hv.z; acc.w += w * hv.w;
    }
    float inv = 1.f / (z + 1e-16f);
    acc.x *= inv; acc.y *= inv; acc.z *= inv; acc.w *= inv;

    if (accumulate) {
        float4 p = ((const float4*)out)[(size_t)d * 32 + lane];
        acc.x += p.x; acc.y += p.y; acc.z += p.z; acc.w += p.w;
    }
    if (b1) {
        float4 bv = ((const float4*)b1)[lane];
        acc.x += bv.x; acc.y += bv.y; acc.z += bv.z; acc.w += bv.w;
    }
    if (b2) {
        float4 bv = ((const float4*)b2)[lane];
        acc.x += bv.x; acc.y += bv.y; acc.z += bv.z; acc.w += bv.w;
    }
    if (act) {
        acc.x = acc.x > 0.f ? acc.x : 0.01f * acc.x;
        acc.y = acc.y > 0.f ? acc.y : 0.01f * acc.y;
        acc.z = acc.z > 0.f ? acc.z : 0.01f * acc.z;
        acc.w = acc.w > 0.f ? acc.w : 0.01f * acc.w;
    }
    ((float4*)out)[(size_t)d * 32 + lane] = acc;
}

// lin_W [128,349] f32 -> bf16 hi/lo pair, TRANSPOSED to [n=384][k=128]
// (n-major so MFMA B-fragments are contiguous 8-k runs); lin_b -> f32 [384].
__global__ __launch_bounds__(256) void pad_w(
    const float* __restrict__ Wl, const float* __restrict__ bl,
    ushort* __restrict__ Whi, ushort* __restrict__ Wlo, float* __restrict__ bp)
{
    int i = blockIdx.x * 256 + threadIdx.x;
    if (i >= 384 * 128) return;
    int n = i >> 7, k = i & 127;
    float w = (n < 349) ? Wl[k * 349 + n] : 0.0f;
    ushort h = f2bf(w);
    Whi[i] = h;
    Wlo[i] = f2bf(w - bf2f(h));
    if (i < 384) bp[i] = (i < 349) ? bl[i] : 0.0f;
}

// out[100000,349] f32 = X[100000,128] f32 @ W[128,349] f32 + b
// Split-bf16 MFMA: X = Xhi+Xlo, W = Whi+Wlo (bf16 RNE + bf16 residual);
// C = Xhi*Whi + Xhi*Wlo + Xlo*Whi via mfma_f32_16x16x32_bf16 (f32 accum,
// dropped lo*lo term ~2^-16 relative). k-permutation within the fragment is
// identical for A and B operands -> cancels; relies only on m89-verified C/D
// layout (col=lane&15, row=(lane>>4)*4+reg) and A-rows/B-cols on lane&15.
// 64 rows/block, 4 waves, wave w owns cols w*96..w*96+95 (4x6 16x16 tiles).
// A staged in LDS bf16 with XOR swizzle (byte ^= (row&7)<<4) to break the
// 256B-stride bank conflict; B-frags read from L2-resident (196 KB) global.
__global__ __launch_bounds__(256) void gemm_out(
    const float* __restrict__ X, const ushort* __restrict__ Whi,
    const ushort* __restrict__ Wlo, const float* __restrict__ bp,
    float* __restrict__ out)
{
    __shared__ ushort sAhi[64 * 128];   // 16 KB
    __shared__ ushort sAlo[64 * 128];   // 16 KB
    const int tid = threadIdx.x;
    const size_t r0 = (size_t)blockIdx.x * 64;

    {   // stage + split-convert X tile (64 rows x 128 k), coalesced reads
        const int rl = tid >> 2, sub = tid & 3;   // row-local, k-quarter
        const size_t row = r0 + rl;
        const float4* Xr = (const float4*)(X + row * 128);
        const u32 swz = ((u32)(rl & 7)) << 4;
        const float4 z4 = make_float4(0.f, 0.f, 0.f, 0.f);
#pragma unroll
        for (int i = 0; i < 4; ++i) {
            float4 u0 = (row < NN) ? Xr[sub * 8 + 2 * i] : z4;
            float4 u1 = (row < NN) ? Xr[sub * 8 + 2 * i + 1] : z4;
            float v[8] = {u0.x, u0.y, u0.z, u0.w, u1.x, u1.y, u1.z, u1.w};
            bf16x8 h8, l8;
#pragma unroll
            for (int e = 0; e < 8; ++e) {
                ushort h = f2bf(v[e]);
                h8[e] = (short)h;
                l8[e] = (short)f2bf(v[e] - bf2f(h));
            }
            u32 byteoff = ((u32)rl * 256u + (u32)((sub * 32 + i * 8) * 2)) ^ swz;
            *(bf16x8*)((char*)sAhi + byteoff) = h8;
            *(bf16x8*)((char*)sAlo + byteoff) = l8;
        }
    }
    __syncthreads();

    const int wave = tid >> 6, lane = tid & 63;
    const int lr = lane & 15;    // A-row / B-col / C-col within 16-tile
    const int lg = lane >> 4;    // k-group (8 k's each) / C row-group
    const int ncol0 = wave * 96;

    f32x4 acc[4][6];
#pragma unroll
    for (int mt = 0; mt < 4; ++mt)
#pragma unroll
        for (int nt = 0; nt < 6; ++nt)
            acc[mt][nt] = (f32x4){0.f, 0.f, 0.f, 0.f};

    for (int ks = 0; ks < 4; ++ks) {   // k = ks*32 .. +31
        bf16x8 ah[4], al[4];
#pragma unroll
        for (int mt = 0; mt < 4; ++mt) {
            const int row = mt * 16 + lr;
            u32 byteoff = ((u32)row * 256u + (u32)(ks * 64 + lg * 16))
                          ^ (((u32)(row & 7)) << 4);
            ah[mt] = *(const bf16x8*)((const char*)sAhi + byteoff);
            al[mt] = *(const bf16x8*)((const char*)sAlo + byteoff);
        }
        bf16x8 bh[6], bl6[6];
#pragma unroll
        for (int nt = 0; nt < 6; ++nt) {
            const int n = ncol0 + nt * 16 + lr;
            const size_t off = (size_t)n * 128 + ks * 32 + lg * 8;
            bh[nt]  = *(const bf16x8*)(Whi + off);
            bl6[nt] = *(const bf16x8*)(Wlo + off);
        }
#pragma unroll
        for (int mt = 0; mt < 4; ++mt)
#pragma unroll
            for (int nt = 0; nt < 6; ++nt) {
                acc[mt][nt] = __builtin_amdgcn_mfma_f32_16x16x32_bf16(
                    ah[mt], bh[nt], acc[mt][nt], 0, 0, 0);
                acc[mt][nt] = __builtin_amdgcn_mfma_f32_16x16x32_bf16(
                    ah[mt], bl6[nt], acc[mt][nt], 0, 0, 0);
                acc[mt][nt] = __builtin_amdgcn_mfma_f32_16x16x32_bf16(
                    al[mt], bh[nt], acc[mt][nt], 0, 0, 0);
            }
    }

#pragma unroll
    for (int nt = 0; nt < 6; ++nt) {
        const int n = ncol0 + nt * 16 + lr;
        if (n >= 349) continue;
        const float bb = bp[n];
#pragma unroll
        for (int mt = 0; mt < 4; ++mt) {
#pragma unroll
            for (int r = 0; r < 4; ++r) {
                const size_t row = r0 + mt * 16 + lg * 4 + r;
                if (row < NN)
                    out[row * 349 + n] = acc[mt][nt][r] + bb;
            }
        }
    }
}

extern "C" void kernel_launch(void* const* d_in, const int* in_sizes, int n_in,
                              void* d_out, int out_size, void* d_ws, size_t ws_size,
                              hipStream_t stream)
{
    (void)in_sizes; (void)n_in; (void)out_size; (void)ws_size;
    const float* xp = (const float*)d_in[0];
    const float* xa = (const float*)d_in[1];
    const int* eic = (const int*)d_in[2];
    const int* eiw = (const int*)d_in[3];
    const int* eiwb = (const int*)d_in[4];
    auto Wl = [&](int l, int r) { return (const float*)d_in[5 + (l * 3 + r) * 4 + 0]; };
    auto As = [&](int l, int r) { return (const float*)d_in[5 + (l * 3 + r) * 4 + 1]; };
    auto Ad = [&](int l, int r) { return (const float*)d_in[5 + (l * 3 + r) * 4 + 2]; };
    auto Bs = [&](int l, int r) { return (const float*)d_in[5 + (l * 3 + r) * 4 + 3]; };
    const float* linW = (const float*)d_in[29];
    const float* linb = (const float*)d_in[30];

    char* wsp = (char*)d_ws;
    auto carve = [&](size_t bytes) -> void* {
        void* p = (void*)wsp;
        wsp += (bytes + 255) & ~(size_t)255;
        return p;
    };
    float* Hs = (float*)carve((size_t)NN * 128 * 4);   // per-relation transformed feats
    float* P1 = (float*)carve((size_t)NN * 128 * 4);   // paper layer0 out
    float* A1 = (float*)carve((size_t)NN * 128 * 4);   // author layer0 out
    float* P2 = (float*)carve((size_t)NN * 128 * 4);   // paper layer1 out
    // one contiguous carve for all 3 degree arrays so one exact-size memset
    // zeroes everything
    int* deg = (int*)carve((size_t)NN * 3 * 4);
    int* deg_c = deg, *deg_w = deg + NN, *deg_wb = deg + 2 * NN;
    int* bkt_c = (int*)carve((size_t)NN * CAP * 4);
    int* bkt_w = (int*)carve((size_t)NN * CAP * 4);
    int* bkt_wb = (int*)carve((size_t)NN * CAP * 4);
    float* aS = (float*)carve((size_t)NN * 4 * 4);
    float* aD = (float*)carve((size_t)NN * 4 * 4);
    float* aX = (float*)carve((size_t)NN * 4 * 4);     // shared sink (never read)
    ushort* Whi = (ushort*)carve((size_t)384 * 128 * 2);
    ushort* Wlo = (ushort*)carve((size_t)384 * 128 * 2);
    float* bp = (float*)carve((size_t)384 * 4);
    float* Wf = (float*)carve((size_t)3 * 512 * 4);    // att-folded dst-side W x3

    dim3 blk(256);
    const int gG = NN / 32;             // 3125
    const int gE = (EE + 255) / 256;    // 977
    const int gA = NN * 32 / 256;       // 12500
    const int gO = (NN + 63) / 64;      // 1563

    // ---- bucket build + all weight folds (layer-invariant / input-only) ----
    hipMemsetAsync(deg, 0, (size_t)NN * 3 * 4, stream);
    fill_buckets<<<gE, blk, 0, stream>>>(eic, deg_c, bkt_c);
    fill_buckets<<<gE, blk, 0, stream>>>(eiw, deg_w, bkt_w);
    fill_buckets<<<gE, blk, 0, stream>>>(eiwb, deg_wb, bkt_wb);
    fold_w3<<<6, blk, 0, stream>>>(Wl(0, 2), Ad(0, 2), Wl(0, 1), Ad(0, 1),
                                   Wl(1, 1), Ad(1, 1), Wf);

    // ---- layer 0: written_by (paper -> author) ----
    gemm_att<<<gG, blk, 0, stream>>>(xp, Wl(0, 2), As(0, 2), Ad(0, 2), Hs, aS, aX);
    gemv_att<<<gA, blk, 0, stream>>>(xa, Wf + 0 * 512, aD);
    aggregate<<<gA, blk, 0, stream>>>(deg_wb, bkt_wb, aS, aD, Hs, A1, 0, Bs(0, 2), nullptr, 1);

    // ---- layer 0: cites (paper -> paper) ----
    gemm_att<<<gG, blk, 0, stream>>>(xp, Wl(0, 0), As(0, 0), Ad(0, 0), Hs, aS, aD);
    aggregate<<<gA, blk, 0, stream>>>(deg_c, bkt_c, aS, aD, Hs, P1, 0, nullptr, nullptr, 0);

    // ---- layer 0: writes (author -> paper), fuse biases + act ----
    gemm_att<<<gG, blk, 0, stream>>>(xa, Wl(0, 1), As(0, 1), Ad(0, 1), Hs, aS, aX);
    gemv_att<<<gA, blk, 0, stream>>>(xp, Wf + 1 * 512, aD);
    aggregate<<<gA, blk, 0, stream>>>(deg_w, bkt_w, aS, aD, Hs, P1, 1, Bs(0, 0), Bs(0, 1), 1);

    // ---- layer 1 (author output is dead code -> skip written_by) ----
    gemm_att<<<gG, blk, 0, stream>>>(P1, Wl(1, 0), As(1, 0), Ad(1, 0), Hs, aS, aD);
    aggregate<<<gA, blk, 0, stream>>>(deg_c, bkt_c, aS, aD, Hs, P2, 0, nullptr, nullptr, 0);

    gemm_att<<<gG, blk, 0, stream>>>(A1, Wl(1, 1), As(1, 1), Ad(1, 1), Hs, aS, aX);
    gemv_att<<<gA, blk, 0, stream>>>(P1, Wf + 2 * 512, aD);
    aggregate<<<gA, blk, 0, stream>>>(deg_w, bkt_w, aS, aD, Hs, P2, 1, Bs(1, 0), Bs(1, 1), 0);

    // ---- classifier head ----
    pad_w<<<192, blk, 0, stream>>>(linW, linb, Whi, Wlo, bp);
    gemm_out<<<gO, blk, 0, stream>>>(P2, Whi, Wlo, bp, (float*)d_out);
}

// Round 7
// 879.916 us; speedup vs baseline: 1.2509x; 1.0887x over previous
//
#include <hip/hip_runtime.h>

#define NN 100000
#define EE 250000
#define CAP 32

typedef unsigned int u32;
typedef unsigned short ushort;
typedef __attribute__((ext_vector_type(8))) short bf16x8;
typedef __attribute__((ext_vector_type(4))) float f32x4;

__device__ __forceinline__ ushort f2bf(float x) {   // f32 -> bf16 RNE
    u32 u = __float_as_uint(x);
    return (ushort)((u + 0x7fffu + ((u >> 16) & 1u)) >> 16);
}
__device__ __forceinline__ float bf2f(ushort h) {
    return __uint_as_float(((u32)h) << 16);
}

// H = X @ W  (X: [NN,128] f32, W: [128,128] f32), plus attention scalars.
// In-place H==X is SAFE: each block stages its own 32 rows to LDS before
// any H write, and no block touches another block's rows.
__global__ __launch_bounds__(256) void gemm_att(
    const float* __restrict__ X, const float* __restrict__ W,
    const float* __restrict__ atts, const float* __restrict__ attd,
    float* __restrict__ H, float* __restrict__ aS, float* __restrict__ aD)
{
    __shared__ float sW[64 * 128];    // 32 KB (half of W at a time)
    __shared__ float sXT[128 * 32];   // 16 KB transposed: [k][row]
    const int tid = threadIdx.x;
    const size_t r0 = (size_t)blockIdx.x * 32;

    {   // stage X tile (32 rows x 128) transposed
        int rl = tid & 31, kg = tid >> 5;   // kg 0..7
        const float4* Xr = (const float4*)(X + (r0 + rl) * 128);
#pragma unroll
        for (int t = 0; t < 4; ++t) {
            float4 u = Xr[kg * 4 + t];
            int k = kg * 16 + t * 4;
            sXT[(k + 0) * 32 + rl] = u.x;
            sXT[(k + 1) * 32 + rl] = u.y;
            sXT[(k + 2) * 32 + rl] = u.z;
            sXT[(k + 3) * 32 + rl] = u.w;
        }
    }

    const int jg = tid & 31;   // 4 cols: jg*4 .. jg*4+3
    const int rg = tid >> 5;   // 4 rows: rg*4 .. rg*4+3
    float acc[4][4] = {};

    for (int kh = 0; kh < 2; ++kh) {
        __syncthreads();
        const float4* Wu = (const float4*)(W + kh * 64 * 128);
        float4* sWv = (float4*)sW;
#pragma unroll
        for (int t = 0; t < 8; ++t)
            sWv[tid + 256 * t] = Wu[tid + 256 * t];
        __syncthreads();
#pragma unroll 4
        for (int k = 0; k < 64; ++k) {
            const float4 w = ((const float4*)sW)[k * 32 + jg];
            const int kk = kh * 64 + k;
            const float4 x = ((const float4*)sXT)[kk * 8 + rg];  // rows rg*4..+3
            acc[0][0] += w.x * x.x; acc[0][1] += w.y * x.x; acc[0][2] += w.z * x.x; acc[0][3] += w.w * x.x;
            acc[1][0] += w.x * x.y; acc[1][1] += w.y * x.y; acc[1][2] += w.z * x.y; acc[1][3] += w.w * x.y;
            acc[2][0] += w.x * x.z; acc[2][1] += w.y * x.z; acc[2][2] += w.z * x.z; acc[2][3] += w.w * x.z;
            acc[3][0] += w.x * x.w; acc[3][1] += w.y * x.w; acc[3][2] += w.z * x.w; acc[3][3] += w.w * x.w;
        }
    }

    const float4 sv = ((const float4*)atts)[jg];   // atts[jg*4 .. +3]
    const float4 dv = ((const float4*)attd)[jg];
    const int h = jg >> 3;                          // head = (jg*4)>>5

#pragma unroll
    for (int i = 0; i < 4; ++i) {
        const size_t row = r0 + rg * 4 + i;
        if (H)
            ((float4*)H)[row * 32 + jg] = make_float4(acc[i][0], acc[i][1], acc[i][2], acc[i][3]);
        float ps = acc[i][0] * sv.x + acc[i][1] * sv.y + acc[i][2] * sv.z + acc[i][3] * sv.w;
        float pd = acc[i][0] * dv.x + acc[i][1] * dv.y + acc[i][2] * dv.z + acc[i][3] * dv.w;
        // reduce across 8 consecutive lanes sharing (row, head)
        ps += __shfl_xor(ps, 1); ps += __shfl_xor(ps, 2); ps += __shfl_xor(ps, 4);
        pd += __shfl_xor(pd, 1); pd += __shfl_xor(pd, 2); pd += __shfl_xor(pd, 4);
        if ((jg & 7) == 0) {
            aS[row * 4 + h] = ps;
            aD[row * 4 + h] = pd;
        }
    }
}

// Wf[r][k][h] = sum_c Wr[k][h*32+c] * ar[h][c] for the 3 dst-side relations.
__global__ __launch_bounds__(256) void fold_w3(
    const float* __restrict__ W0, const float* __restrict__ a0,
    const float* __restrict__ W1, const float* __restrict__ a1,
    const float* __restrict__ W2, const float* __restrict__ a2,
    float* __restrict__ Wf)   // [3][128][4]
{
    int i = blockIdx.x * 256 + threadIdx.x;
    if (i >= 1536) return;
    int r = i >> 9, j = i & 511;
    int k = j >> 2, h = j & 3;
    const float* W = (r == 0) ? W0 : (r == 1) ? W1 : W2;
    const float* a = (r == 0) ? a0 : (r == 1) ? a1 : a2;
    float s = 0.f;
#pragma unroll
    for (int c = 0; c < 32; ++c)
        s += W[k * 128 + h * 32 + c] * a[h * 32 + c];
    Wf[i] = s;
}

// aD[n][h] = sum_k X[n][k] * Wf[k][h] — dst-side attention scalar.
__global__ __launch_bounds__(256) void gemv_att(
    const float* __restrict__ X, const float* __restrict__ Wf,
    float* __restrict__ aD)
{
    __shared__ float sWf[512];
    const int tid = threadIdx.x;
    if (tid < 128)
        ((float4*)sWf)[tid] = ((const float4*)Wf)[tid];
    __syncthreads();
    const int t = blockIdx.x * 256 + tid;
    const int n = t >> 5, lane = t & 31;
    if (n >= NN) return;
    const float4 x = ((const float4*)X)[(size_t)n * 32 + lane];
    const float4 w0 = ((const float4*)sWf)[lane * 4 + 0];
    const float4 w1 = ((const float4*)sWf)[lane * 4 + 1];
    const float4 w2 = ((const float4*)sWf)[lane * 4 + 2];
    const float4 w3 = ((const float4*)sWf)[lane * 4 + 3];
    float p0 = x.x * w0.x + x.y * w1.x + x.z * w2.x + x.w * w3.x;
    float p1 = x.x * w0.y + x.y * w1.y + x.z * w2.y + x.w * w3.y;
    float p2 = x.x * w0.z + x.y * w1.z + x.z * w2.z + x.w * w3.z;
    float p3 = x.x * w0.w + x.y * w1.w + x.z * w2.w + x.w * w3.w;
#pragma unroll
    for (int off = 1; off < 32; off <<= 1) {
        p0 += __shfl_xor(p0, off);
        p1 += __shfl_xor(p1, off);
        p2 += __shfl_xor(p2, off);
        p3 += __shfl_xor(p3, off);
    }
    if (lane == 0)
        ((float4*)aD)[n] = make_float4(p0, p1, p2, p3);
}

// per-dst incoming-edge buckets (gather-based aggregation; no feature atomics)
__global__ __launch_bounds__(256) void fill_buckets(
    const int* __restrict__ ei, int* __restrict__ deg, int* __restrict__ bkt)
{
    int e = blockIdx.x * 256 + threadIdx.x;
    if (e >= EE) return;
    int s = ei[e], d = ei[EE + e];
    int slot = atomicAdd(&deg[d], 1);
    if (slot >= 0 && slot < CAP) bkt[(size_t)d * CAP + slot] = s;  // P(deg>32)~1e-19
}

// one relation's softmax-gather for dst d, lane-owned feature quad `lane`.
// 8-edge register-cached head (P(g>8)~0.2% Poisson-2.5), tail fallback.
__device__ __forceinline__ float4 agg_one(
    int d, int lane, int h,
    const int* __restrict__ deg, const int* __restrict__ bkt,
    const float* __restrict__ aS, const float* __restrict__ aD,
    const float* __restrict__ Hs)
{
    int g = deg[d]; if (g > CAP) g = CAP; if (g < 0) g = 0;
    const float adh = aD[d * 4 + h];
    const int* mybkt = bkt + (size_t)d * CAP;

    const int4 sa = *(const int4*)mybkt;        // slots 0..3
    const int4 sb = *(const int4*)(mybkt + 4);  // slots 4..7
    int sidx[8] = {sa.x, sa.y, sa.z, sa.w, sb.x, sb.y, sb.z, sb.w};
#pragma unroll
    for (int j = 0; j < 8; ++j)
        sidx[j] = (j < g) ? sidx[j] : 0;        // clamp -> loads always valid

    float e[8];
#pragma unroll
    for (int j = 0; j < 8; ++j) {               // 8 independent aS loads
        float ev = aS[sidx[j] * 4 + h] + adh;
        e[j] = ev > 0.f ? ev : 0.2f * ev;
    }
    float m = -INFINITY;
#pragma unroll
    for (int j = 0; j < 8; ++j)
        if (j < g) m = fmaxf(m, e[j]);
    for (int j = 8; j < g; ++j) {               // ultra-rare tail
        int s = mybkt[j];
        float ev = aS[s * 4 + h] + adh;
        ev = ev > 0.f ? ev : 0.2f * ev;
        m = fmaxf(m, ev);
    }

    float4 acc = make_float4(0.f, 0.f, 0.f, 0.f);
    float z = 0.f;
#pragma unroll
    for (int j = 0; j < 8; ++j) {
        if (j < g) {
            float w = __expf(e[j] - m);
            z += w;
            float4 hv = ((const float4*)Hs)[(size_t)sidx[j] * 32 + lane];
            acc.x += w * hv.x; acc.y += w * hv.y; acc.z += w * hv.z; acc.w += w * hv.w;
        }
    }
    for (int j = 8; j < g; ++j) {               // ultra-rare tail
        int s = mybkt[j];
        float ev = aS[s * 4 + h] + adh;
        ev = ev > 0.f ? ev : 0.2f * ev;
        float w = __expf(ev - m);
        z += w;
        float4 hv = ((const float4*)Hs)[(size_t)s * 32 + lane];
        acc.x += w * hv.x; acc.y += w * hv.y; acc.z += w * hv.z; acc.w += w * hv.w;
    }
    float inv = 1.f / (z + 1e-16f);
    acc.x *= inv; acc.y *= inv; acc.z *= inv; acc.w *= inv;
    return acc;
}

// single-relation aggregate (written_by path): + bias + act, fresh write.
__global__ __launch_bounds__(256) void aggregate(
    const int* __restrict__ deg, const int* __restrict__ bkt,
    const float* __restrict__ aS, const float* __restrict__ aD,
    const float* __restrict__ Hs, float* __restrict__ out,
    const float* __restrict__ b1, int act)
{
    int t = blockIdx.x * 256 + threadIdx.x;
    int d = t >> 5, lane = t & 31;
    if (d >= NN) return;
    const int h = lane >> 3;
    float4 acc = agg_one(d, lane, h, deg, bkt, aS, aD, Hs);
    if (b1) {
        float4 bv = ((const float4*)b1)[lane];
        acc.x += bv.x; acc.y += bv.y; acc.z += bv.z; acc.w += bv.w;
    }
    if (act) {
        acc.x = acc.x > 0.f ? acc.x : 0.01f * acc.x;
        acc.y = acc.y > 0.f ? acc.y : 0.01f * acc.y;
        acc.z = acc.z > 0.f ? acc.z : 0.01f * acc.z;
        acc.w = acc.w > 0.f ? acc.w : 0.01f * acc.w;
    }
    ((float4*)out)[(size_t)d * 32 + lane] = acc;
}

// merged two-relation aggregate (paper dst: cites + writes) — replaces the
// old pair {aggregate(c, fresh-write), aggregate(w, accumulate)}: removes a
// full 51MB intermediate write + 51MB read. Add order replicates the old
// sequence exactly (acc_w += acc_c, then b1, b2, act) -> bit-identical.
__global__ __launch_bounds__(256) void aggregate2(
    const int* __restrict__ deg_c, const int* __restrict__ bkt_c,
    const float* __restrict__ aS_c, const float* __restrict__ aD_c,
    const float* __restrict__ Hs_c,
    const int* __restrict__ deg_w, const int* __restrict__ bkt_w,
    const float* __restrict__ aS_w, const float* __restrict__ aD_w,
    const float* __restrict__ Hs_w,
    float* __restrict__ out,
    const float* __restrict__ b1, const float* __restrict__ b2, int act)
{
    int t = blockIdx.x * 256 + threadIdx.x;
    int d = t >> 5, lane = t & 31;
    if (d >= NN) return;
    const int h = lane >> 3;
    float4 acc_c = agg_one(d, lane, h, deg_c, bkt_c, aS_c, aD_c, Hs_c);
    float4 acc  = agg_one(d, lane, h, deg_w, bkt_w, aS_w, aD_w, Hs_w);
    acc.x += acc_c.x; acc.y += acc_c.y; acc.z += acc_c.z; acc.w += acc_c.w;
    {
        float4 bv = ((const float4*)b1)[lane];
        acc.x += bv.x; acc.y += bv.y; acc.z += bv.z; acc.w += bv.w;
    }
    {
        float4 bv = ((const float4*)b2)[lane];
        acc.x += bv.x; acc.y += bv.y; acc.z += bv.z; acc.w += bv.w;
    }
    if (act) {
        acc.x = acc.x > 0.f ? acc.x : 0.01f * acc.x;
        acc.y = acc.y > 0.f ? acc.y : 0.01f * acc.y;
        acc.z = acc.z > 0.f ? acc.z : 0.01f * acc.z;
        acc.w = acc.w > 0.f ? acc.w : 0.01f * acc.w;
    }
    ((float4*)out)[(size_t)d * 32 + lane] = acc;
}

// lin_W [128,349] f32 -> bf16 hi/lo pair, TRANSPOSED to [n=384][k=128];
// lin_b -> f32 [384].
__global__ __launch_bounds__(256) void pad_w(
    const float* __restrict__ Wl, const float* __restrict__ bl,
    ushort* __restrict__ Whi, ushort* __restrict__ Wlo, float* __restrict__ bp)
{
    int i = blockIdx.x * 256 + threadIdx.x;
    if (i >= 384 * 128) return;
    int n = i >> 7, k = i & 127;
    float w = (n < 349) ? Wl[k * 349 + n] : 0.0f;
    ushort h = f2bf(w);
    Whi[i] = h;
    Wlo[i] = f2bf(w - bf2f(h));
    if (i < 384) bp[i] = (i < 349) ? bl[i] : 0.0f;
}

// out[100000,349] = X[100000,128] @ W + b, split-bf16 MFMA (same math as R6).
// v3 fixes R6's two measured problems:
//  - WRITE_SIZE 250MB (scalar 64B strided stores): epilogue now stages each
//    16-row chunk in LDS packed [16][349] and writes 1396 contiguous float4
//    (chunk base = multiple of 22336B -> 16B aligned) -> full sectors.
//  - occupancy 17.7% (96 AGPR): 32-row blocks, wave = 2mt x 6nt = 48 AGPR.
// NN = 3125*32 exactly -> no row guards.
__global__ __launch_bounds__(256) void gemm_out(
    const float* __restrict__ X, const ushort* __restrict__ Whi,
    const ushort* __restrict__ Wlo, const float* __restrict__ bp,
    float* __restrict__ out)
{
    __shared__ __align__(16) char smem[22400];   // max(16KB stage, 21.9KB epi)
    ushort* sAhi = (ushort*)smem;                // [32][128] bf16 swizzled, 8KB
    ushort* sAlo = (ushort*)(smem + 8192);       // 8KB
    float*  sOut = (float*)smem;                 // epilogue alias [16*349]
    const int tid = threadIdx.x;
    const size_t r0 = (size_t)blockIdx.x * 32;

    {   // stage + split-convert X tile (32 rows x 128 k)
        const int rl = tid >> 3, sub = tid & 7;
        const float4* Xr = (const float4*)(X + (r0 + rl) * 128);
        const u32 swz = ((u32)(rl & 7)) << 4;
#pragma unroll
        for (int i = 0; i < 2; ++i) {
            float4 u0 = Xr[sub * 4 + 2 * i];
            float4 u1 = Xr[sub * 4 + 2 * i + 1];
            float v[8] = {u0.x, u0.y, u0.z, u0.w, u1.x, u1.y, u1.z, u1.w};
            bf16x8 h8, l8;
#pragma unroll
            for (int e = 0; e < 8; ++e) {
                ushort h = f2bf(v[e]);
                h8[e] = (short)h;
                l8[e] = (short)f2bf(v[e] - bf2f(h));
            }
            u32 byteoff = (((u32)rl * 256u) + (u32)(sub * 32 + i * 16)) ^ swz;
            *(bf16x8*)((char*)sAhi + byteoff) = h8;
            *(bf16x8*)((char*)sAlo + byteoff) = l8;
        }
    }
    __syncthreads();

    const int wave = tid >> 6, lane = tid & 63;
    const int lr = lane & 15;    // A-row / B-col within 16-tile
    const int lg = lane >> 4;    // k-group / C row-group
    const int ncol0 = wave * 96;

    f32x4 acc[2][6];
#pragma unroll
    for (int mt = 0; mt < 2; ++mt)
#pragma unroll
        for (int nt = 0; nt < 6; ++nt)
            acc[mt][nt] = (f32x4){0.f, 0.f, 0.f, 0.f};

    for (int ks = 0; ks < 4; ++ks) {   // k = ks*32 .. +31
        bf16x8 ah[2], al[2];
#pragma unroll
        for (int mt = 0; mt < 2; ++mt) {
            const int row = mt * 16 + lr;
            u32 byteoff = (((u32)row * 256u) + (u32)(ks * 64 + lg * 16))
                          ^ (((u32)(row & 7)) << 4);
            ah[mt] = *(const bf16x8*)((const char*)sAhi + byteoff);
            al[mt] = *(const bf16x8*)((const char*)sAlo + byteoff);
        }
#pragma unroll
        for (int nt = 0; nt < 6; ++nt) {
            const int n = ncol0 + nt * 16 + lr;
            const size_t off = (size_t)n * 128 + ks * 32 + lg * 8;
            const bf16x8 bh = *(const bf16x8*)(Whi + off);
            const bf16x8 bl = *(const bf16x8*)(Wlo + off);
#pragma unroll
            for (int mt = 0; mt < 2; ++mt) {
                acc[mt][nt] = __builtin_amdgcn_mfma_f32_16x16x32_bf16(
                    ah[mt], bh, acc[mt][nt], 0, 0, 0);
                acc[mt][nt] = __builtin_amdgcn_mfma_f32_16x16x32_bf16(
                    ah[mt], bl, acc[mt][nt], 0, 0, 0);
                acc[mt][nt] = __builtin_amdgcn_mfma_f32_16x16x32_bf16(
                    al[mt], bh, acc[mt][nt], 0, 0, 0);
            }
        }
    }
    __syncthreads();   // all waves done reading A staging

    for (int mt = 0; mt < 2; ++mt) {
        if (mt) __syncthreads();   // previous chunk copy done before overwrite
#pragma unroll
        for (int nt = 0; nt < 6; ++nt) {
            const int n = ncol0 + nt * 16 + lr;
            if (n < 349) {
                const float bb = bp[n];
#pragma unroll
                for (int r = 0; r < 4; ++r)
                    sOut[(lg * 4 + r) * 349 + n] = acc[mt][nt][r] + bb;
            }
        }
        __syncthreads();
        {   // 16 rows x 349 = 5584 floats = 1396 float4, contiguous + aligned
            float4* dst = (float4*)(out + (r0 + (size_t)mt * 16) * 349);
            const float4* src = (const float4*)sOut;
            for (int i = tid; i < 1396; i += 256)
                dst[i] = src[i];
        }
    }
}

extern "C" void kernel_launch(void* const* d_in, const int* in_sizes, int n_in,
                              void* d_out, int out_size, void* d_ws, size_t ws_size,
                              hipStream_t stream)
{
    (void)in_sizes; (void)n_in; (void)out_size; (void)ws_size;
    const float* xp = (const float*)d_in[0];
    const float* xa = (const float*)d_in[1];
    const int* eic = (const int*)d_in[2];
    const int* eiw = (const int*)d_in[3];
    const int* eiwb = (const int*)d_in[4];
    auto Wl = [&](int l, int r) { return (const float*)d_in[5 + (l * 3 + r) * 4 + 0]; };
    auto As = [&](int l, int r) { return (const float*)d_in[5 + (l * 3 + r) * 4 + 1]; };
    auto Ad = [&](int l, int r) { return (const float*)d_in[5 + (l * 3 + r) * 4 + 2]; };
    auto Bs = [&](int l, int r) { return (const float*)d_in[5 + (l * 3 + r) * 4 + 3]; };
    const float* linW = (const float*)d_in[29];
    const float* linb = (const float*)d_in[30];

    char* wsp = (char*)d_ws;
    auto carve = [&](size_t bytes) -> void* {
        void* p = (void*)wsp;
        wsp += (bytes + 255) & ~(size_t)255;
        return p;
    };
    float* Hs = (float*)carve((size_t)NN * 128 * 4);   // cites-relation feats
    float* P1 = (float*)carve((size_t)NN * 128 * 4);   // paper layer0 out
    float* A1 = (float*)carve((size_t)NN * 128 * 4);   // author layer0 out
    float* P2 = (float*)carve((size_t)NN * 128 * 4);   // layer0: writes-Hs; layer1: paper out
    int* deg = (int*)carve((size_t)NN * 3 * 4);        // contiguous -> one memset
    int* deg_c = deg, *deg_w = deg + NN, *deg_wb = deg + 2 * NN;
    int* bkt_c = (int*)carve((size_t)NN * CAP * 4);
    int* bkt_w = (int*)carve((size_t)NN * CAP * 4);
    int* bkt_wb = (int*)carve((size_t)NN * CAP * 4);
    float* aS = (float*)carve((size_t)NN * 4 * 4);
    float* aD = (float*)carve((size_t)NN * 4 * 4);
    float* aS2 = (float*)carve((size_t)NN * 4 * 4);
    float* aD2 = (float*)carve((size_t)NN * 4 * 4);
    float* aX = (float*)carve((size_t)NN * 4 * 4);     // shared sink (never read)
    ushort* Whi = (ushort*)carve((size_t)384 * 128 * 2);
    ushort* Wlo = (ushort*)carve((size_t)384 * 128 * 2);
    float* bp = (float*)carve((size_t)384 * 4);
    float* Wf = (float*)carve((size_t)3 * 512 * 4);    // att-folded dst-side W x3

    dim3 blk(256);
    const int gG = NN / 32;             // 3125
    const int gE = (EE + 255) / 256;    // 977
    const int gA = NN * 32 / 256;       // 12500

    // ---- bucket build + weight folds (input-only) ----
    hipMemsetAsync(deg, 0, (size_t)NN * 3 * 4, stream);
    fill_buckets<<<gE, blk, 0, stream>>>(eic, deg_c, bkt_c);
    fill_buckets<<<gE, blk, 0, stream>>>(eiw, deg_w, bkt_w);
    fill_buckets<<<gE, blk, 0, stream>>>(eiwb, deg_wb, bkt_wb);
    fold_w3<<<6, blk, 0, stream>>>(Wl(0, 2), Ad(0, 2), Wl(0, 1), Ad(0, 1),
                                   Wl(1, 1), Ad(1, 1), Wf);

    // ---- layer 0: written_by (paper -> author) ----
    gemm_att<<<gG, blk, 0, stream>>>(xp, Wl(0, 2), As(0, 2), Ad(0, 2), Hs, aS, aX);
    gemv_att<<<gA, blk, 0, stream>>>(xa, Wf + 0 * 512, aD);
    aggregate<<<gA, blk, 0, stream>>>(deg_wb, bkt_wb, aS, aD, Hs, A1, Bs(0, 2), 1);

    // ---- layer 0: paper (cites + writes merged) ----
    gemm_att<<<gG, blk, 0, stream>>>(xp, Wl(0, 0), As(0, 0), Ad(0, 0), Hs, aS, aD);
    gemm_att<<<gG, blk, 0, stream>>>(xa, Wl(0, 1), As(0, 1), Ad(0, 1), P2, aS2, aX);
    gemv_att<<<gA, blk, 0, stream>>>(xp, Wf + 1 * 512, aD2);
    aggregate2<<<gA, blk, 0, stream>>>(deg_c, bkt_c, aS, aD, Hs,
                                       deg_w, bkt_w, aS2, aD2, P2,
                                       P1, Bs(0, 0), Bs(0, 1), 1);

    // ---- layer 1: paper (cites + writes merged; author out is dead code) ----
    gemm_att<<<gG, blk, 0, stream>>>(P1, Wl(1, 0), As(1, 0), Ad(1, 0), Hs, aS, aD);
    gemm_att<<<gG, blk, 0, stream>>>(A1, Wl(1, 1), As(1, 1), Ad(1, 1), A1, aS2, aX);  // in-place
    gemv_att<<<gA, blk, 0, stream>>>(P1, Wf + 2 * 512, aD2);
    aggregate2<<<gA, blk, 0, stream>>>(deg_c, bkt_c, aS, aD, Hs,
                                       deg_w, bkt_w, aS2, aD2, A1,
                                       P2, Bs(1, 0), Bs(1, 1), 0);

    // ---- classifier head ----
    pad_w<<<192, blk, 0, stream>>>(linW, linb, Whi, Wlo, bp);
    gemm_out<<<gG, blk, 0, stream>>>(P2, Whi, Wlo, bp, (float*)d_out);
}

// Round 8
// 822.800 us; speedup vs baseline: 1.3377x; 1.0694x over previous
//
#include <hip/hip_runtime.h>

#define NN 100000
#define EE 250000
#define CAP 32

typedef unsigned int u32;
typedef unsigned short ushort;
typedef __attribute__((ext_vector_type(8))) short bf16x8;
typedef __attribute__((ext_vector_type(4))) float f32x4;

__device__ __forceinline__ ushort f2bf(float x) {   // f32 -> bf16 RNE
    u32 u = __float_as_uint(x);
    return (ushort)((u + 0x7fffu + ((u >> 16) & 1u)) >> 16);
}
__device__ __forceinline__ float bf2f(ushort h) {
    return __uint_as_float(((u32)h) << 16);
}

// 5 relation weights [128k][128n] f32 -> bf16 hi/lo, transposed to [n][k]
// (n-major so MFMA B-fragments are contiguous 8-k runs). 5*32KB, L2-hot.
__global__ __launch_bounds__(256) void prep_w5(
    const float* __restrict__ W0, const float* __restrict__ W1,
    const float* __restrict__ W2, const float* __restrict__ W3,
    const float* __restrict__ W4,
    ushort* __restrict__ Whi, ushort* __restrict__ Wlo)
{
    int i = blockIdx.x * 256 + threadIdx.x;
    if (i >= 5 * 16384) return;
    int r = i >> 14, j = i & 16383;
    int n = j >> 7, k = j & 127;
    const float* W = (r == 0) ? W0 : (r == 1) ? W1 : (r == 2) ? W2
                   : (r == 3) ? W3 : W4;
    float w = W[k * 128 + n];
    ushort h = f2bf(w);
    Whi[i] = h;
    Wlo[i] = f2bf(w - bf2f(h));
}

// H = X @ W + attention scalars, split-bf16 MFMA (same 3-term scheme and
// fragment addressing as gemm_out, harness-validated since R6).
// 32-row blocks, 4 waves; wave w owns cols w*32..+31 == head w, so
// aS/aD reduce fully within 16-lane groups (4 shfl_xor), no cross-wave.
// In-place H==X is SAFE: block stages its 32 rows to LDS before writing.
__global__ __launch_bounds__(256) void gemm_att(
    const float* __restrict__ X, const ushort* __restrict__ Whi,
    const ushort* __restrict__ Wlo, const float* __restrict__ atts,
    const float* __restrict__ attd, float* __restrict__ H,
    float* __restrict__ aS, float* __restrict__ aD)
{
    __shared__ ushort sAhi[32 * 128];   // 8 KB, XOR-swizzled
    __shared__ ushort sAlo[32 * 128];   // 8 KB
    const int tid = threadIdx.x;
    const size_t r0 = (size_t)blockIdx.x * 32;   // NN = 3125*32 exactly

    {   // stage + split-convert X tile (32 rows x 128 k)
        const int rl = tid >> 3, sub = tid & 7;
        const float4* Xr = (const float4*)(X + (r0 + rl) * 128);
        const u32 swz = ((u32)(rl & 7)) << 4;
#pragma unroll
        for (int i = 0; i < 2; ++i) {
            float4 u0 = Xr[sub * 4 + 2 * i];
            float4 u1 = Xr[sub * 4 + 2 * i + 1];
            float v[8] = {u0.x, u0.y, u0.z, u0.w, u1.x, u1.y, u1.z, u1.w};
            bf16x8 h8, l8;
#pragma unroll
            for (int e = 0; e < 8; ++e) {
                ushort h = f2bf(v[e]);
                h8[e] = (short)h;
                l8[e] = (short)f2bf(v[e] - bf2f(h));
            }
            u32 byteoff = (((u32)rl * 256u) + (u32)(sub * 32 + i * 16)) ^ swz;
            *(bf16x8*)((char*)sAhi + byteoff) = h8;
            *(bf16x8*)((char*)sAlo + byteoff) = l8;
        }
    }
    __syncthreads();

    const int wave = tid >> 6, lane = tid & 63;
    const int lr = lane & 15;    // A-row / B-col within 16-tile
    const int lg = lane >> 4;    // k-group / C row-group
    const int ncol0 = wave * 32; // this wave's cols == head `wave`

    f32x4 acc[2][2];
#pragma unroll
    for (int mt = 0; mt < 2; ++mt)
#pragma unroll
        for (int nt = 0; nt < 2; ++nt)
            acc[mt][nt] = (f32x4){0.f, 0.f, 0.f, 0.f};

    for (int ks = 0; ks < 4; ++ks) {   // k = ks*32 .. +31
        bf16x8 ah[2], al[2];
#pragma unroll
        for (int mt = 0; mt < 2; ++mt) {
            const int row = mt * 16 + lr;
            u32 byteoff = (((u32)row * 256u) + (u32)(ks * 64 + lg * 16))
                          ^ (((u32)(row & 7)) << 4);
            ah[mt] = *(const bf16x8*)((const char*)sAhi + byteoff);
            al[mt] = *(const bf16x8*)((const char*)sAlo + byteoff);
        }
#pragma unroll
        for (int nt = 0; nt < 2; ++nt) {
            const int n = ncol0 + nt * 16 + lr;
            const size_t off = (size_t)n * 128 + ks * 32 + lg * 8;
            const bf16x8 bh = *(const bf16x8*)(Whi + off);
            const bf16x8 bl = *(const bf16x8*)(Wlo + off);
#pragma unroll
            for (int mt = 0; mt < 2; ++mt) {
                acc[mt][nt] = __builtin_amdgcn_mfma_f32_16x16x32_bf16(
                    ah[mt], bh, acc[mt][nt], 0, 0, 0);
                acc[mt][nt] = __builtin_amdgcn_mfma_f32_16x16x32_bf16(
                    ah[mt], bl, acc[mt][nt], 0, 0, 0);
                acc[mt][nt] = __builtin_amdgcn_mfma_f32_16x16x32_bf16(
                    al[mt], bh, acc[mt][nt], 0, 0, 0);
            }
        }
    }

    // epilogue: H writes (aligned 64B per 16-lane group) + per-head scalars
    const float sv0 = atts[ncol0 + lr],      sv1 = atts[ncol0 + 16 + lr];
    const float dv0 = attd[ncol0 + lr],      dv1 = attd[ncol0 + 16 + lr];
#pragma unroll
    for (int mt = 0; mt < 2; ++mt) {
#pragma unroll
        for (int r = 0; r < 4; ++r) {
            const size_t grow = r0 + mt * 16 + lg * 4 + r;
            H[grow * 128 + ncol0 + lr]      = acc[mt][0][r];
            H[grow * 128 + ncol0 + 16 + lr] = acc[mt][1][r];
            float ps = acc[mt][0][r] * sv0 + acc[mt][1][r] * sv1;
            float pd = acc[mt][0][r] * dv0 + acc[mt][1][r] * dv1;
            ps += __shfl_xor(ps, 1); ps += __shfl_xor(ps, 2);
            ps += __shfl_xor(ps, 4); ps += __shfl_xor(ps, 8);
            pd += __shfl_xor(pd, 1); pd += __shfl_xor(pd, 2);
            pd += __shfl_xor(pd, 4); pd += __shfl_xor(pd, 8);
            if (lr == 0) {
                aS[grow * 4 + wave] = ps;
                aD[grow * 4 + wave] = pd;
            }
        }
    }
}

// Wf[r][k][h] = sum_c Wr[k][h*32+c] * ar[h][c] for the 3 dst-side relations.
__global__ __launch_bounds__(256) void fold_w3(
    const float* __restrict__ W0, const float* __restrict__ a0,
    const float* __restrict__ W1, const float* __restrict__ a1,
    const float* __restrict__ W2, const float* __restrict__ a2,
    float* __restrict__ Wf)   // [3][128][4]
{
    int i = blockIdx.x * 256 + threadIdx.x;
    if (i >= 1536) return;
    int r = i >> 9, j = i & 511;
    int k = j >> 2, h = j & 3;
    const float* W = (r == 0) ? W0 : (r == 1) ? W1 : W2;
    const float* a = (r == 0) ? a0 : (r == 1) ? a1 : a2;
    float s = 0.f;
#pragma unroll
    for (int c = 0; c < 32; ++c)
        s += W[k * 128 + h * 32 + c] * a[h * 32 + c];
    Wf[i] = s;
}

// aD[n][h] = sum_k X[n][k] * Wf[k][h] — dst-side attention scalar.
__global__ __launch_bounds__(256) void gemv_att(
    const float* __restrict__ X, const float* __restrict__ Wf,
    float* __restrict__ aD)
{
    __shared__ float sWf[512];
    const int tid = threadIdx.x;
    if (tid < 128)
        ((float4*)sWf)[tid] = ((const float4*)Wf)[tid];
    __syncthreads();
    const int t = blockIdx.x * 256 + tid;
    const int n = t >> 5, lane = t & 31;
    if (n >= NN) return;
    const float4 x = ((const float4*)X)[(size_t)n * 32 + lane];
    const float4 w0 = ((const float4*)sWf)[lane * 4 + 0];
    const float4 w1 = ((const float4*)sWf)[lane * 4 + 1];
    const float4 w2 = ((const float4*)sWf)[lane * 4 + 2];
    const float4 w3 = ((const float4*)sWf)[lane * 4 + 3];
    float p0 = x.x * w0.x + x.y * w1.x + x.z * w2.x + x.w * w3.x;
    float p1 = x.x * w0.y + x.y * w1.y + x.z * w2.y + x.w * w3.y;
    float p2 = x.x * w0.z + x.y * w1.z + x.z * w2.z + x.w * w3.z;
    float p3 = x.x * w0.w + x.y * w1.w + x.z * w2.w + x.w * w3.w;
#pragma unroll
    for (int off = 1; off < 32; off <<= 1) {
        p0 += __shfl_xor(p0, off);
        p1 += __shfl_xor(p1, off);
        p2 += __shfl_xor(p2, off);
        p3 += __shfl_xor(p3, off);
    }
    if (lane == 0)
        ((float4*)aD)[n] = make_float4(p0, p1, p2, p3);
}

// per-dst incoming-edge buckets (gather-based aggregation; no feature atomics)
__global__ __launch_bounds__(256) void fill_buckets(
    const int* __restrict__ ei, int* __restrict__ deg, int* __restrict__ bkt)
{
    int e = blockIdx.x * 256 + threadIdx.x;
    if (e >= EE) return;
    int s = ei[e], d = ei[EE + e];
    int slot = atomicAdd(&deg[d], 1);
    if (slot >= 0 && slot < CAP) bkt[(size_t)d * CAP + slot] = s;  // P(deg>32)~1e-19
}

// one relation's softmax-gather for dst d, lane-owned feature quad `lane`.
// 8-edge register-cached head (P(g>8)~0.2% Poisson-2.5), tail fallback.
__device__ __forceinline__ float4 agg_one(
    int d, int lane, int h,
    const int* __restrict__ deg, const int* __restrict__ bkt,
    const float* __restrict__ aS, const float* __restrict__ aD,
    const float* __restrict__ Hs)
{
    int g = deg[d]; if (g > CAP) g = CAP; if (g < 0) g = 0;
    const float adh = aD[d * 4 + h];
    const int* mybkt = bkt + (size_t)d * CAP;

    const int4 sa = *(const int4*)mybkt;        // slots 0..3
    const int4 sb = *(const int4*)(mybkt + 4);  // slots 4..7
    int sidx[8] = {sa.x, sa.y, sa.z, sa.w, sb.x, sb.y, sb.z, sb.w};
#pragma unroll
    for (int j = 0; j < 8; ++j)
        sidx[j] = (j < g) ? sidx[j] : 0;        // clamp -> loads always valid

    float e[8];
#pragma unroll
    for (int j = 0; j < 8; ++j) {               // 8 independent aS loads
        float ev = aS[sidx[j] * 4 + h] + adh;
        e[j] = ev > 0.f ? ev : 0.2f * ev;
    }
    float m = -INFINITY;
#pragma unroll
    for (int j = 0; j < 8; ++j)
        if (j < g) m = fmaxf(m, e[j]);
    for (int j = 8; j < g; ++j) {               // ultra-rare tail
        int s = mybkt[j];
        float ev = aS[s * 4 + h] + adh;
        ev = ev > 0.f ? ev : 0.2f * ev;
        m = fmaxf(m, ev);
    }

    float4 acc = make_float4(0.f, 0.f, 0.f, 0.f);
    float z = 0.f;
#pragma unroll
    for (int j = 0; j < 8; ++j) {
        if (j < g) {
            float w = __expf(e[j] - m);
            z += w;
            float4 hv = ((const float4*)Hs)[(size_t)sidx[j] * 32 + lane];
            acc.x += w * hv.x; acc.y += w * hv.y; acc.z += w * hv.z; acc.w += w * hv.w;
        }
    }
    for (int j = 8; j < g; ++j) {               // ultra-rare tail
        int s = mybkt[j];
        float ev = aS[s * 4 + h] + adh;
        ev = ev > 0.f ? ev : 0.2f * ev;
        float w = __expf(ev - m);
        z += w;
        float4 hv = ((const float4*)Hs)[(size_t)s * 32 + lane];
        acc.x += w * hv.x; acc.y += w * hv.y; acc.z += w * hv.z; acc.w += w * hv.w;
    }
    float inv = 1.f / (z + 1e-16f);
    acc.x *= inv; acc.y *= inv; acc.z *= inv; acc.w *= inv;
    return acc;
}

// single-relation aggregate (written_by path): + bias + act, fresh write.
__global__ __launch_bounds__(256) void aggregate(
    const int* __restrict__ deg, const int* __restrict__ bkt,
    const float* __restrict__ aS, const float* __restrict__ aD,
    const float* __restrict__ Hs, float* __restrict__ out,
    const float* __restrict__ b1, int act)
{
    int t = blockIdx.x * 256 + threadIdx.x;
    int d = t >> 5, lane = t & 31;
    if (d >= NN) return;
    const int h = lane >> 3;
    float4 acc = agg_one(d, lane, h, deg, bkt, aS, aD, Hs);
    if (b1) {
        float4 bv = ((const float4*)b1)[lane];
        acc.x += bv.x; acc.y += bv.y; acc.z += bv.z; acc.w += bv.w;
    }
    if (act) {
        acc.x = acc.x > 0.f ? acc.x : 0.01f * acc.x;
        acc.y = acc.y > 0.f ? acc.y : 0.01f * acc.y;
        acc.z = acc.z > 0.f ? acc.z : 0.01f * acc.z;
        acc.w = acc.w > 0.f ? acc.w : 0.01f * acc.w;
    }
    ((float4*)out)[(size_t)d * 32 + lane] = acc;
}

// merged two-relation aggregate (paper dst: cites + writes); add order
// replicates the old sequential pair exactly -> bit-identical.
__global__ __launch_bounds__(256) void aggregate2(
    const int* __restrict__ deg_c, const int* __restrict__ bkt_c,
    const float* __restrict__ aS_c, const float* __restrict__ aD_c,
    const float* __restrict__ Hs_c,
    const int* __restrict__ deg_w, const int* __restrict__ bkt_w,
    const float* __restrict__ aS_w, const float* __restrict__ aD_w,
    const float* __restrict__ Hs_w,
    float* __restrict__ out,
    const float* __restrict__ b1, const float* __restrict__ b2, int act)
{
    int t = blockIdx.x * 256 + threadIdx.x;
    int d = t >> 5, lane = t & 31;
    if (d >= NN) return;
    const int h = lane >> 3;
    float4 acc_c = agg_one(d, lane, h, deg_c, bkt_c, aS_c, aD_c, Hs_c);
    float4 acc  = agg_one(d, lane, h, deg_w, bkt_w, aS_w, aD_w, Hs_w);
    acc.x += acc_c.x; acc.y += acc_c.y; acc.z += acc_c.z; acc.w += acc_c.w;
    {
        float4 bv = ((const float4*)b1)[lane];
        acc.x += bv.x; acc.y += bv.y; acc.z += bv.z; acc.w += bv.w;
    }
    {
        float4 bv = ((const float4*)b2)[lane];
        acc.x += bv.x; acc.y += bv.y; acc.z += bv.z; acc.w += bv.w;
    }
    if (act) {
        acc.x = acc.x > 0.f ? acc.x : 0.01f * acc.x;
        acc.y = acc.y > 0.f ? acc.y : 0.01f * acc.y;
        acc.z = acc.z > 0.f ? acc.z : 0.01f * acc.z;
        acc.w = acc.w > 0.f ? acc.w : 0.01f * acc.w;
    }
    ((float4*)out)[(size_t)d * 32 + lane] = acc;
}

// lin_W [128,349] f32 -> bf16 hi/lo pair, TRANSPOSED to [n=384][k=128];
// lin_b -> f32 [384].
__global__ __launch_bounds__(256) void pad_w(
    const float* __restrict__ Wl, const float* __restrict__ bl,
    ushort* __restrict__ Whi, ushort* __restrict__ Wlo, float* __restrict__ bp)
{
    int i = blockIdx.x * 256 + threadIdx.x;
    if (i >= 384 * 128) return;
    int n = i >> 7, k = i & 127;
    float w = (n < 349) ? Wl[k * 349 + n] : 0.0f;
    ushort h = f2bf(w);
    Whi[i] = h;
    Wlo[i] = f2bf(w - bf2f(h));
    if (i < 384) bp[i] = (i < 349) ? bl[i] : 0.0f;
}

// out[100000,349] = X[100000,128] @ W + b, split-bf16 MFMA.
// Epilogue copy now dword-strided (consecutive lanes -> consecutive banks):
// R7's float4 copy had lanes 0,8,16.. on the same bank quad (8-way, 2.3M
// conflicts). Global writes still coalesce to 1KB/wave.
__global__ __launch_bounds__(256) void gemm_out(
    const float* __restrict__ X, const ushort* __restrict__ Whi,
    const ushort* __restrict__ Wlo, const float* __restrict__ bp,
    float* __restrict__ out)
{
    __shared__ __align__(16) char smem[22400];   // max(16KB stage, 21.9KB epi)
    ushort* sAhi = (ushort*)smem;                // [32][128] bf16 swizzled, 8KB
    ushort* sAlo = (ushort*)(smem + 8192);       // 8KB
    float*  sOut = (float*)smem;                 // epilogue alias [16*349]
    const int tid = threadIdx.x;
    const size_t r0 = (size_t)blockIdx.x * 32;

    {   // stage + split-convert X tile (32 rows x 128 k)
        const int rl = tid >> 3, sub = tid & 7;
        const float4* Xr = (const float4*)(X + (r0 + rl) * 128);
        const u32 swz = ((u32)(rl & 7)) << 4;
#pragma unroll
        for (int i = 0; i < 2; ++i) {
            float4 u0 = Xr[sub * 4 + 2 * i];
            float4 u1 = Xr[sub * 4 + 2 * i + 1];
            float v[8] = {u0.x, u0.y, u0.z, u0.w, u1.x, u1.y, u1.z, u1.w};
            bf16x8 h8, l8;
#pragma unroll
            for (int e = 0; e < 8; ++e) {
                ushort h = f2bf(v[e]);
                h8[e] = (short)h;
                l8[e] = (short)f2bf(v[e] - bf2f(h));
            }
            u32 byteoff = (((u32)rl * 256u) + (u32)(sub * 32 + i * 16)) ^ swz;
            *(bf16x8*)((char*)sAhi + byteoff) = h8;
            *(bf16x8*)((char*)sAlo + byteoff) = l8;
        }
    }
    __syncthreads();

    const int wave = tid >> 6, lane = tid & 63;
    const int lr = lane & 15;    // A-row / B-col within 16-tile
    const int lg = lane >> 4;    // k-group / C row-group
    const int ncol0 = wave * 96;

    f32x4 acc[2][6];
#pragma unroll
    for (int mt = 0; mt < 2; ++mt)
#pragma unroll
        for (int nt = 0; nt < 6; ++nt)
            acc[mt][nt] = (f32x4){0.f, 0.f, 0.f, 0.f};

    for (int ks = 0; ks < 4; ++ks) {   // k = ks*32 .. +31
        bf16x8 ah[2], al[2];
#pragma unroll
        for (int mt = 0; mt < 2; ++mt) {
            const int row = mt * 16 + lr;
            u32 byteoff = (((u32)row * 256u) + (u32)(ks * 64 + lg * 16))
                          ^ (((u32)(row & 7)) << 4);
            ah[mt] = *(const bf16x8*)((const char*)sAhi + byteoff);
            al[mt] = *(const bf16x8*)((const char*)sAlo + byteoff);
        }
#pragma unroll
        for (int nt = 0; nt < 6; ++nt) {
            const int n = ncol0 + nt * 16 + lr;
            const size_t off = (size_t)n * 128 + ks * 32 + lg * 8;
            const bf16x8 bh = *(const bf16x8*)(Whi + off);
            const bf16x8 bl = *(const bf16x8*)(Wlo + off);
#pragma unroll
            for (int mt = 0; mt < 2; ++mt) {
                acc[mt][nt] = __builtin_amdgcn_mfma_f32_16x16x32_bf16(
                    ah[mt], bh, acc[mt][nt], 0, 0, 0);
                acc[mt][nt] = __builtin_amdgcn_mfma_f32_16x16x32_bf16(
                    ah[mt], bl, acc[mt][nt], 0, 0, 0);
                acc[mt][nt] = __builtin_amdgcn_mfma_f32_16x16x32_bf16(
                    al[mt], bh, acc[mt][nt], 0, 0, 0);
            }
        }
    }
    __syncthreads();   // all waves done reading A staging

    for (int mt = 0; mt < 2; ++mt) {
        if (mt) __syncthreads();   // previous chunk copy done before overwrite
#pragma unroll
        for (int nt = 0; nt < 6; ++nt) {
            const int n = ncol0 + nt * 16 + lr;
            if (n < 349) {
                const float bb = bp[n];
#pragma unroll
                for (int r = 0; r < 4; ++r)
                    sOut[(lg * 4 + r) * 349 + n] = acc[mt][nt][r] + bb;
            }
        }
        __syncthreads();
        {   // 16 rows x 349 = 5584 floats; dword copy, conflict-free
            float* dst = out + (r0 + (size_t)mt * 16) * 349;
            for (int i = tid; i < 5584; i += 256)
                dst[i] = sOut[i];
        }
    }
}

extern "C" void kernel_launch(void* const* d_in, const int* in_sizes, int n_in,
                              void* d_out, int out_size, void* d_ws, size_t ws_size,
                              hipStream_t stream)
{
    (void)in_sizes; (void)n_in; (void)out_size; (void)ws_size;
    const float* xp = (const float*)d_in[0];
    const float* xa = (const float*)d_in[1];
    const int* eic = (const int*)d_in[2];
    const int* eiw = (const int*)d_in[3];
    const int* eiwb = (const int*)d_in[4];
    auto Wl = [&](int l, int r) { return (const float*)d_in[5 + (l * 3 + r) * 4 + 0]; };
    auto As = [&](int l, int r) { return (const float*)d_in[5 + (l * 3 + r) * 4 + 1]; };
    auto Ad = [&](int l, int r) { return (const float*)d_in[5 + (l * 3 + r) * 4 + 2]; };
    auto Bs = [&](int l, int r) { return (const float*)d_in[5 + (l * 3 + r) * 4 + 3]; };
    const float* linW = (const float*)d_in[29];
    const float* linb = (const float*)d_in[30];

    char* wsp = (char*)d_ws;
    auto carve = [&](size_t bytes) -> void* {
        void* p = (void*)wsp;
        wsp += (bytes + 255) & ~(size_t)255;
        return p;
    };
    float* Hs = (float*)carve((size_t)NN * 128 * 4);   // cites-relation feats
    float* P1 = (float*)carve((size_t)NN * 128 * 4);   // paper layer0 out
    float* A1 = (float*)carve((size_t)NN * 128 * 4);   // author layer0 out
    float* P2 = (float*)carve((size_t)NN * 128 * 4);   // layer0: writes-Hs; layer1: paper out
    int* deg = (int*)carve((size_t)NN * 3 * 4);        // contiguous -> one memset
    int* deg_c = deg, *deg_w = deg + NN, *deg_wb = deg + 2 * NN;
    int* bkt_c = (int*)carve((size_t)NN * CAP * 4);
    int* bkt_w = (int*)carve((size_t)NN * CAP * 4);
    int* bkt_wb = (int*)carve((size_t)NN * CAP * 4);
    float* aS = (float*)carve((size_t)NN * 4 * 4);
    float* aD = (float*)carve((size_t)NN * 4 * 4);
    float* aS2 = (float*)carve((size_t)NN * 4 * 4);
    float* aD2 = (float*)carve((size_t)NN * 4 * 4);
    float* aX = (float*)carve((size_t)NN * 4 * 4);     // shared sink (never read)
    ushort* Whi = (ushort*)carve((size_t)384 * 128 * 2);
    ushort* Wlo = (ushort*)carve((size_t)384 * 128 * 2);
    float* bp = (float*)carve((size_t)384 * 4);
    float* Wf = (float*)carve((size_t)3 * 512 * 4);    // att-folded dst-side W x3
    ushort* Whi5 = (ushort*)carve((size_t)5 * 16384 * 2);  // relation W, bf16-split [n][k]
    ushort* Wlo5 = (ushort*)carve((size_t)5 * 16384 * 2);

    dim3 blk(256);
    const int gG = NN / 32;             // 3125
    const int gE = (EE + 255) / 256;    // 977
    const int gA = NN * 32 / 256;       // 12500

    // ---- bucket build + weight prep (input-only) ----
    hipMemsetAsync(deg, 0, (size_t)NN * 3 * 4, stream);
    fill_buckets<<<gE, blk, 0, stream>>>(eic, deg_c, bkt_c);
    fill_buckets<<<gE, blk, 0, stream>>>(eiw, deg_w, bkt_w);
    fill_buckets<<<gE, blk, 0, stream>>>(eiwb, deg_wb, bkt_wb);
    fold_w3<<<6, blk, 0, stream>>>(Wl(0, 2), Ad(0, 2), Wl(0, 1), Ad(0, 1),
                                   Wl(1, 1), Ad(1, 1), Wf);
    prep_w5<<<320, blk, 0, stream>>>(Wl(0, 2), Wl(0, 0), Wl(0, 1),
                                     Wl(1, 0), Wl(1, 1), Whi5, Wlo5);

    // ---- layer 0: written_by (paper -> author) ----
    gemm_att<<<gG, blk, 0, stream>>>(xp, Whi5 + 0 * 16384, Wlo5 + 0 * 16384,
                                     As(0, 2), Ad(0, 2), Hs, aS, aX);
    gemv_att<<<gA, blk, 0, stream>>>(xa, Wf + 0 * 512, aD);
    aggregate<<<gA, blk, 0, stream>>>(deg_wb, bkt_wb, aS, aD, Hs, A1, Bs(0, 2), 1);

    // ---- layer 0: paper (cites + writes merged) ----
    gemm_att<<<gG, blk, 0, stream>>>(xp, Whi5 + 1 * 16384, Wlo5 + 1 * 16384,
                                     As(0, 0), Ad(0, 0), Hs, aS, aD);
    gemm_att<<<gG, blk, 0, stream>>>(xa, Whi5 + 2 * 16384, Wlo5 + 2 * 16384,
                                     As(0, 1), Ad(0, 1), P2, aS2, aX);
    gemv_att<<<gA, blk, 0, stream>>>(xp, Wf + 1 * 512, aD2);
    aggregate2<<<gA, blk, 0, stream>>>(deg_c, bkt_c, aS, aD, Hs,
                                       deg_w, bkt_w, aS2, aD2, P2,
                                       P1, Bs(0, 0), Bs(0, 1), 1);

    // ---- layer 1: paper (cites + writes merged; author out is dead code) ----
    gemm_att<<<gG, blk, 0, stream>>>(P1, Whi5 + 3 * 16384, Wlo5 + 3 * 16384,
                                     As(1, 0), Ad(1, 0), Hs, aS, aD);
    gemm_att<<<gG, blk, 0, stream>>>(A1, Whi5 + 4 * 16384, Wlo5 + 4 * 16384,
                                     As(1, 1), Ad(1, 1), A1, aS2, aX);  // in-place
    gemv_att<<<gA, blk, 0, stream>>>(P1, Wf + 2 * 512, aD2);
    aggregate2<<<gA, blk, 0, stream>>>(deg_c, bkt_c, aS, aD, Hs,
                                       deg_w, bkt_w, aS2, aD2, A1,
                                       P2, Bs(1, 0), Bs(1, 1), 0);

    // ---- classifier head ----
    pad_w<<<192, blk, 0, stream>>>(linW, linb, Whi, Wlo, bp);
    gemm_out<<<gG, blk, 0, stream>>>(P2, Whi, Wlo, bp, (float*)d_out);
}